// Round 1
// baseline (2813.595 us; speedup 1.0000x reference)
//
#include <hip/hip_runtime.h>

// Dilated RNN forward, MI355X. Strategy:
//  - per-layer kernel; WG = 8 waves = 16 rows of one dilation chain
//  - h state in ping-pong LDS; Whh/Wih as persistent register B-fragments
//  - fp32-accurate via bf16 hi/lo split (3 MFMA products)
//  - inter-layer activations as pre-split bf16 hi/lo planes in d_ws (~196 MB)

typedef __attribute__((ext_vector_type(8))) short bf16x8;
typedef __attribute__((ext_vector_type(4))) float f32x4;

#define TSTEPS 784
#define NBATCH 256
#define HID 128

__device__ __forceinline__ unsigned short f32_to_bf16(float f) {
  unsigned int u = __builtin_bit_cast(unsigned int, f);
  u = (u + 0x7FFFu + ((u >> 16) & 1u)) >> 16;  // round-to-nearest-even
  return (unsigned short)u;
}
__device__ __forceinline__ float bf16_to_f32(unsigned short s) {
  unsigned int u = ((unsigned int)s) << 16;
  return __builtin_bit_cast(float, u);
}
__device__ __forceinline__ float tanh_fast(float v) {
  // tanh(v) = 1 - 2/(e^{2v}+1); abs err ~1e-7, safe for |v| < 40
  float t = __expf(2.0f * v);
  return 1.0f - __fdividef(2.0f, t + 1.0f);
}
// load 8 consecutive f32 weights -> hi/lo bf16 fragment slots
__device__ __forceinline__ void load_wfrag(const float* __restrict__ p, bf16x8& hi, bf16x8& lo) {
#pragma unroll
  for (int i = 0; i < 8; ++i) {
    float v = p[i];
    unsigned short h = f32_to_bf16(v);
    float rem = v - bf16_to_f32(h);
    hi[i] = (short)h;
    lo[i] = (short)f32_to_bf16(rem);
  }
}

// One dilated-RNN layer. Grid: 16*rate WGs of 512 threads.
// WG wg: chain c = wg>>4, batches b0..b0+15 (b0 = (wg&15)*16).
// Wave w computes output hidden columns [16w, 16w+16).
// MFMA orientation: M = 16 rows (batch), N = 16 cols (hidden out), K = hidden in.
// A-frag: lane holds row (lane&15), k-slice by (lane>>4)  [mirrored with B => k-map cancels]
// C-frag (measured m89): value r of lane l -> row (l>>4)*4+r, col l&15.
template<int LAYER0, int LAST>
__global__ __launch_bounds__(512) void drnn_layer(
    const float* __restrict__ x0,              // LAYER0: x (B,T) fp32
    const unsigned short* __restrict__ Yin_hi, // else: prev layer hi plane [T][B][H]
    const unsigned short* __restrict__ Yin_lo,
    unsigned short* __restrict__ Yout_hi,
    unsigned short* __restrict__ Yout_lo,
    float* __restrict__ hlast,                 // LAST: t=783 output, f32 [B][H]
    const float* __restrict__ Wih,
    const float* __restrict__ Whh,
    const float* __restrict__ bih,
    const float* __restrict__ bhh,
    int rate)
{
  // 136-short pitch: row starts 272B apart -> 16B-aligned b128 reads, lane-group
  // (lrow+lgrp) mixing keeps each 8-lane service group on distinct bank quads.
  __shared__ __align__(16) unsigned short Hhi[2][16][136];
  __shared__ __align__(16) unsigned short Hlo[2][16][136];

  const int tid  = threadIdx.x;
  const int wave = tid >> 6;
  const int lane = tid & 63;
  const int lrow = lane & 15;
  const int lgrp = lane >> 4;
  const int ncol = wave * 16 + lrow;   // this lane's C column (hidden out)
  const int wg    = blockIdx.x;
  const int chain = wg >> 4;
  const int b0    = (wg & 15) << 4;
  const int jmax  = (TSTEPS - chain + rate - 1) / rate;  // skip padded tail steps

  // ---- persistent weight fragments (B-operand: B[k][n] = W[n][k]) ----
  bf16x8 whhh[4], whhl[4], wihh[4], wihl[4];
#pragma unroll
  for (int kb = 0; kb < 4; ++kb)
    load_wfrag(Whh + (size_t)ncol * HID + kb * 32 + lgrp * 8, whhh[kb], whhl[kb]);
  if (!LAYER0) {
#pragma unroll
    for (int kb = 0; kb < 4; ++kb)
      load_wfrag(Wih + (size_t)ncol * HID + kb * 32 + lgrp * 8, wihh[kb], wihl[kb]);
  }
  const float w0   = LAYER0 ? Wih[ncol] : 0.0f;   // Wih0 is (128,1)
  const float bias = bih[ncol] + bhh[ncol];

  // double-buffered x prefetch (static register sets; manual 2-step unroll)
  bf16x8 xhA[4], xlA[4], xhB[4], xlB[4];
  float  xvA[4], xvB[4];

  if (LAYER0) {
#pragma unroll
    for (int r = 0; r < 4; ++r)
      xvA[r] = x0[(size_t)(b0 + lgrp * 4 + r) * TSTEPS + chain];
  } else {
    const size_t base = ((size_t)chain * NBATCH + (b0 + lrow)) * HID + lgrp * 8;
#pragma unroll
    for (int kb = 0; kb < 4; ++kb) {
      xhA[kb] = *(const bf16x8*)(Yin_hi + base + kb * 32);
      xlA[kb] = *(const bf16x8*)(Yin_lo + base + kb * 32);
    }
  }

  auto step = [&](int j, auto& xh_c, auto& xl_c, auto& xh_n, auto& xl_n,
                  auto& xv_c, auto& xv_n) {
    const int t = j * rate + chain;
    // prefetch x for step j+1 (off the critical chain)
    if (j + 1 < jmax) {
      const int tn = t + rate;
      if (LAYER0) {
#pragma unroll
        for (int r = 0; r < 4; ++r)
          xv_n[r] = x0[(size_t)(b0 + lgrp * 4 + r) * TSTEPS + tn];
      } else {
        const size_t base = ((size_t)tn * NBATCH + (b0 + lrow)) * HID + lgrp * 8;
#pragma unroll
        for (int kb = 0; kb < 4; ++kb) {
          xh_n[kb] = *(const bf16x8*)(Yin_hi + base + kb * 32);
          xl_n[kb] = *(const bf16x8*)(Yin_lo + base + kb * 32);
        }
      }
    }
    // 3 split-product accumulators -> three parallel 4-deep MFMA chains
    f32x4 c0 = {0.f, 0.f, 0.f, 0.f};
    f32x4 c1 = c0, c2 = c0;
    if (!LAYER0) {  // xW before the barrier: independent of h
#pragma unroll
      for (int kb = 0; kb < 4; ++kb) {
        c0 = __builtin_amdgcn_mfma_f32_16x16x32_bf16(xh_c[kb], wihh[kb], c0, 0, 0, 0);
        c1 = __builtin_amdgcn_mfma_f32_16x16x32_bf16(xh_c[kb], wihl[kb], c1, 0, 0, 0);
        c2 = __builtin_amdgcn_mfma_f32_16x16x32_bf16(xl_c[kb], wihh[kb], c2, 0, 0, 0);
      }
    }
    if (j > 0) {  // h(-1) = 0 -> skip entirely at j==0
      __syncthreads();  // all waves' H[j-1] writes visible (ping-pong => 1 barrier/step)
      const int rp = (j - 1) & 1;
      bf16x8 ah[4], al[4];
#pragma unroll
      for (int kb = 0; kb < 4; ++kb) {
        ah[kb] = *(const bf16x8*)&Hhi[rp][lrow][kb * 32 + lgrp * 8];
        al[kb] = *(const bf16x8*)&Hlo[rp][lrow][kb * 32 + lgrp * 8];
      }
#pragma unroll
      for (int kb = 0; kb < 4; ++kb) {
        c0 = __builtin_amdgcn_mfma_f32_16x16x32_bf16(ah[kb], whhh[kb], c0, 0, 0, 0);
        c1 = __builtin_amdgcn_mfma_f32_16x16x32_bf16(ah[kb], whhl[kb], c1, 0, 0, 0);
        c2 = __builtin_amdgcn_mfma_f32_16x16x32_bf16(al[kb], whhh[kb], c2, 0, 0, 0);
      }
    }
    const int pp = j & 1;
#pragma unroll
    for (int r = 0; r < 4; ++r) {
      float v = c0[r] + c1[r] + c2[r] + bias;
      if (LAYER0) v += xv_c[r] * w0;
      const float y = tanh_fast(v);
      const unsigned short hb = f32_to_bf16(y);
      const unsigned short lb = f32_to_bf16(y - bf16_to_f32(hb));
      const int m = lgrp * 4 + r;           // C row -> batch offset
      Hhi[pp][m][ncol] = hb;
      Hlo[pp][m][ncol] = lb;
      if (!LAST) {
        const size_t e = ((size_t)t * NBATCH + (b0 + m)) * HID + ncol;
        Yout_hi[e] = hb;
        Yout_lo[e] = lb;
      } else if (t == TSTEPS - 1) {
        hlast[(size_t)(b0 + m) * HID + ncol] = y;  // full-precision f32 handoff
      }
    }
  };

  int j = 0;
  for (;;) {
    step(j, xhA, xlA, xhB, xlB, xvA, xvB);
    if (++j >= jmax) break;
    step(j, xhB, xlB, xhA, xlA, xvB, xvA);
    if (++j >= jmax) break;
  }
}

// logits[b][n] = sum_k h[b][k] * W[k][n] + b[n]   (W is (128,10) row-major, no transpose)
__global__ __launch_bounds__(256) void logits_kernel(
    const float* __restrict__ hlast, const float* __restrict__ W,
    const float* __restrict__ bvec, float* __restrict__ out)
{
  __shared__ float Ws[HID * 10];
  const int tid = threadIdx.x;
  for (int i = tid; i < HID * 10; i += 256) Ws[i] = W[i];
  __syncthreads();
  float acc[10];
#pragma unroll
  for (int n = 0; n < 10; ++n) acc[n] = bvec[n];
  const float* h = hlast + (size_t)tid * HID;
#pragma unroll 4
  for (int k = 0; k < HID; ++k) {
    const float hv = h[k];
#pragma unroll
    for (int n = 0; n < 10; ++n) acc[n] += hv * Ws[k * 10 + n];
  }
#pragma unroll
  for (int n = 0; n < 10; ++n) out[(size_t)tid * 10 + n] = acc[n];
}

extern "C" void kernel_launch(void* const* d_in, const int* in_sizes, int n_in,
                              void* d_out, int out_size, void* d_ws, size_t ws_size,
                              hipStream_t stream) {
  (void)in_sizes; (void)n_in; (void)out_size; (void)ws_size;
  const float* x    = (const float*)d_in[0];   // (256,784,1)
  const float* Wih0 = (const float*)d_in[1];   // (128,1)
  const float* Whh0 = (const float*)d_in[2];   // (128,128)
  const float* bih0 = (const float*)d_in[3];
  const float* bhh0 = (const float*)d_in[4];
  const float* WihA = (const float*)d_in[5];   // (7,128,128)
  const float* WhhA = (const float*)d_in[6];   // (7,128,128)
  const float* bihA = (const float*)d_in[7];   // (7,128)
  const float* bhhA = (const float*)d_in[8];   // (7,128)
  const float* Wout = (const float*)d_in[9];   // (128,10)
  const float* bout = (const float*)d_in[10];  // (10,)
  float* out = (float*)d_out;

  // workspace layout: 4 bf16 planes (ping-pong x hi/lo) + hlast f32  (~196 MB)
  const size_t planeElems = (size_t)TSTEPS * NBATCH * HID;  // 25,690,112
  unsigned short* b0hi = (unsigned short*)d_ws;
  unsigned short* b0lo = b0hi + planeElems;
  unsigned short* b1hi = b0lo + planeElems;
  unsigned short* b1lo = b1hi + planeElems;
  float* hlast = (float*)(b1lo + planeElems);

  // layer 0 (rate 1, D=1)
  drnn_layer<1, 0><<<dim3(16), dim3(512), 0, stream>>>(
      x, nullptr, nullptr, b0hi, b0lo, nullptr, Wih0, Whh0, bih0, bhh0, 1);

  unsigned short *cur_hi = b0hi, *cur_lo = b0lo, *alt_hi = b1hi, *alt_lo = b1lo;
  for (int i = 0; i < 7; ++i) {
    const int rate = 2 << i;  // 2,4,8,16,32,64,128
    const float* Wih = WihA + (size_t)i * HID * HID;
    const float* Whh = WhhA + (size_t)i * HID * HID;
    const float* bi  = bihA + (size_t)i * HID;
    const float* bh  = bhhA + (size_t)i * HID;
    if (i < 6) {
      drnn_layer<0, 0><<<dim3(16 * rate), dim3(512), 0, stream>>>(
          nullptr, cur_hi, cur_lo, alt_hi, alt_lo, nullptr, Wih, Whh, bi, bh, rate);
      unsigned short* t1 = cur_hi; cur_hi = alt_hi; alt_hi = t1;
      unsigned short* t2 = cur_lo; cur_lo = alt_lo; alt_lo = t2;
    } else {
      // last layer: only t=783 is consumed; store it as f32, skip plane stores
      drnn_layer<0, 1><<<dim3(16 * rate), dim3(512), 0, stream>>>(
          nullptr, cur_hi, cur_lo, nullptr, nullptr, hlast, Wih, Whh, bi, bh, rate);
    }
  }

  logits_kernel<<<dim3(1), dim3(256), 0, stream>>>(hlast, Wout, bout, out);
}

// Round 3
// 2670.428 us; speedup vs baseline: 1.0536x; 1.0536x over previous
//
#include <hip/hip_runtime.h>

// Dilated RNN forward, MI355X. Round 2 (resubmit — R2 bench never acquired a GPU):
//  - per-layer kernel; WG = 8 waves = 16 rows of one dilation chain
//  - h state in ping-pong LDS; Whh/Wih as persistent register B-fragments
//  - fp32-accurate via bf16 hi/lo split (3 MFMA products)
//  - raw s_barrier with lgkmcnt-only wait (no vmcnt(0) drain per step);
//    plane write-back via coalesced LDS readback (16B/lane), off-chain

typedef __attribute__((ext_vector_type(8))) short bf16x8;
typedef __attribute__((ext_vector_type(4))) float f32x4;

#define TSTEPS 784
#define NBATCH 256
#define HID 128

__device__ __forceinline__ unsigned short f32_to_bf16(float f) {
  unsigned int u = __builtin_bit_cast(unsigned int, f);
  u = (u + 0x7FFFu + ((u >> 16) & 1u)) >> 16;  // round-to-nearest-even
  return (unsigned short)u;
}
__device__ __forceinline__ float bf16_to_f32(unsigned short s) {
  unsigned int u = ((unsigned int)s) << 16;
  return __builtin_bit_cast(float, u);
}
__device__ __forceinline__ float tanh_fast(float v) {
  float t = __expf(2.0f * v);
  return 1.0f - __fdividef(2.0f, t + 1.0f);
}
// LDS-only barrier: wave waits for ITS ds ops, syncs, does NOT drain vmcnt.
// Global loads/stores in flight stay in flight across the barrier (T4).
__device__ __forceinline__ void lds_barrier() {
  asm volatile("s_waitcnt lgkmcnt(0)" ::: "memory");
  __builtin_amdgcn_s_barrier();
  asm volatile("" ::: "memory");
}
// load 8 consecutive f32 weights -> hi/lo bf16 fragment slots
__device__ __forceinline__ void load_wfrag(const float* __restrict__ p, bf16x8& hi, bf16x8& lo) {
#pragma unroll
  for (int i = 0; i < 8; ++i) {
    float v = p[i];
    unsigned short h = f32_to_bf16(v);
    float rem = v - bf16_to_f32(h);
    hi[i] = (short)h;
    lo[i] = (short)f32_to_bf16(rem);
  }
}

// One dilated-RNN layer. Grid: 16*rate WGs of 512 threads.
// WG wg: chain c = wg>>4, batches b0..b0+15 (b0 = (wg&15)*16).
// Wave w computes output hidden columns [16w, 16w+16).
// MFMA: M=16 batch rows, N=16 hidden-out cols, K=hidden-in.
// C-frag (measured m89): value r of lane l -> row (l>>4)*4+r, col l&15.
template<int LAYER0, int LAST>
__global__ __launch_bounds__(512) void drnn_layer(
    const float* __restrict__ x0,              // LAYER0: x (B,T) fp32
    const unsigned short* __restrict__ Yin_hi, // else: prev layer hi plane [T][B][H]
    const unsigned short* __restrict__ Yin_lo,
    unsigned short* __restrict__ Yout_hi,
    unsigned short* __restrict__ Yout_lo,
    float* __restrict__ hlast,                 // LAST: t=783 output, f32 [B][H]
    const float* __restrict__ Wih,
    const float* __restrict__ Whh,
    const float* __restrict__ bih,
    const float* __restrict__ bhh,
    int rate)
{
  // pitch 136 shorts = 272B/row: 16B-aligned b128, (lrow+lgrp) quad mixing
  __shared__ __align__(16) unsigned short Hhi[2][16][136];
  __shared__ __align__(16) unsigned short Hlo[2][16][136];

  const int tid  = threadIdx.x;
  const int wave = tid >> 6;
  const int lane = tid & 63;
  const int lrow = lane & 15;
  const int lgrp = lane >> 4;
  const int ncol = wave * 16 + lrow;   // this lane's C column (hidden out)
  const int wg    = blockIdx.x;
  const int chain = wg >> 4;
  const int b0    = (wg & 15) << 4;
  const int jmax  = (TSTEPS - chain + rate - 1) / rate;  // skip padded tail

  // coalesced plane write-back mapping: waves 0-3 copy hi, 4-7 copy lo;
  // lane slot p covers H[row][cb*8..cb*8+7] -> one 16B store, 1KB/wave contig
  const int p_    = tid & 255;
  const int wrow  = p_ >> 4;
  const int wcb   = p_ & 15;

  // ---- persistent weight fragments (B-operand: B[k][n] = W[n][k]) ----
  bf16x8 whhh[4], whhl[4], wihh[4], wihl[4];
#pragma unroll
  for (int kb = 0; kb < 4; ++kb)
    load_wfrag(Whh + (size_t)ncol * HID + kb * 32 + lgrp * 8, whhh[kb], whhl[kb]);
  if (!LAYER0) {
#pragma unroll
    for (int kb = 0; kb < 4; ++kb)
      load_wfrag(Wih + (size_t)ncol * HID + kb * 32 + lgrp * 8, wihh[kb], wihl[kb]);
  }
  const float w0   = LAYER0 ? Wih[ncol] : 0.0f;   // Wih0 is (128,1)
  const float bias = bih[ncol] + bhh[ncol];

  // double-buffered x prefetch (static register sets; manual 2-step unroll)
  bf16x8 xhA[4], xlA[4], xhB[4], xlB[4];
  float  xvA[4], xvB[4];

  if (LAYER0) {
#pragma unroll
    for (int r = 0; r < 4; ++r)
      xvA[r] = x0[(size_t)(b0 + lgrp * 4 + r) * TSTEPS + chain];
  } else {
    const size_t base = ((size_t)chain * NBATCH + (b0 + lrow)) * HID + lgrp * 8;
#pragma unroll
    for (int kb = 0; kb < 4; ++kb) {
      xhA[kb] = *(const bf16x8*)(Yin_hi + base + kb * 32);
      xlA[kb] = *(const bf16x8*)(Yin_lo + base + kb * 32);
    }
  }

  // coalesced write-back of H[rp] (state of step jsrc) to the output planes.
  // Fire-and-forget: nothing waits on these stores (raw barrier, no vmcnt(0));
  // dispatch-end completion flushes them before the next layer reads.
  auto writeback = [&](int rp, int tsrc) {
    const unsigned short* src =
        (tid < 256 ? &Hhi[rp][0][0] : &Hlo[rp][0][0]) + wrow * 136 + wcb * 8;
    unsigned short* dst =
        (tid < 256 ? Yout_hi : Yout_lo) +
        ((size_t)tsrc * NBATCH + (b0 + wrow)) * HID + wcb * 8;
    *(bf16x8*)dst = *(const bf16x8*)src;
  };

  auto step = [&](int j, auto& xh_c, auto& xl_c, auto& xh_n, auto& xl_n,
                  auto& xv_c, auto& xv_n) {
    const int t = j * rate + chain;
    // prefetch x for step j+1 (off the critical chain; crosses the barrier)
    if (j + 1 < jmax) {
      const int tn = t + rate;
      if (LAYER0) {
#pragma unroll
        for (int r = 0; r < 4; ++r)
          xv_n[r] = x0[(size_t)(b0 + lgrp * 4 + r) * TSTEPS + tn];
      } else {
        const size_t base = ((size_t)tn * NBATCH + (b0 + lrow)) * HID + lgrp * 8;
#pragma unroll
        for (int kb = 0; kb < 4; ++kb) {
          xh_n[kb] = *(const bf16x8*)(Yin_hi + base + kb * 32);
          xl_n[kb] = *(const bf16x8*)(Yin_lo + base + kb * 32);
        }
      }
    }
    // 3 split-product accumulators -> three parallel 4-deep MFMA chains
    f32x4 c0 = {0.f, 0.f, 0.f, 0.f};
    f32x4 c1 = c0, c2 = c0;
    if (!LAYER0) {  // xW before the barrier: independent of h
#pragma unroll
      for (int kb = 0; kb < 4; ++kb) {
        c0 = __builtin_amdgcn_mfma_f32_16x16x32_bf16(xh_c[kb], wihh[kb], c0, 0, 0, 0);
        c1 = __builtin_amdgcn_mfma_f32_16x16x32_bf16(xh_c[kb], wihl[kb], c1, 0, 0, 0);
        c2 = __builtin_amdgcn_mfma_f32_16x16x32_bf16(xl_c[kb], wihh[kb], c2, 0, 0, 0);
      }
    }
    if (j > 0) {
      lds_barrier();  // H[rp] visible; global traffic stays in flight
      const int rp = (j - 1) & 1;
      bf16x8 ah[4], al[4];
#pragma unroll
      for (int kb = 0; kb < 4; ++kb) {
        ah[kb] = *(const bf16x8*)&Hhi[rp][lrow][kb * 32 + lgrp * 8];
        al[kb] = *(const bf16x8*)&Hlo[rp][lrow][kb * 32 + lgrp * 8];
      }
      if (!LAST) writeback(rp, t - rate);  // step j-1 plane store, off-chain
#pragma unroll
      for (int kb = 0; kb < 4; ++kb) {
        c0 = __builtin_amdgcn_mfma_f32_16x16x32_bf16(ah[kb], whhh[kb], c0, 0, 0, 0);
        c1 = __builtin_amdgcn_mfma_f32_16x16x32_bf16(ah[kb], whhl[kb], c1, 0, 0, 0);
        c2 = __builtin_amdgcn_mfma_f32_16x16x32_bf16(al[kb], whhh[kb], c2, 0, 0, 0);
      }
    }
    const int pp = j & 1;
#pragma unroll
    for (int r = 0; r < 4; ++r) {
      float v = c0[r] + c1[r] + c2[r] + bias;
      if (LAYER0) v += xv_c[r] * w0;
      const float y = tanh_fast(v);
      const unsigned short hb = f32_to_bf16(y);
      const unsigned short lb = f32_to_bf16(y - bf16_to_f32(hb));
      const int m = lgrp * 4 + r;           // C row -> batch offset
      Hhi[pp][m][ncol] = hb;
      Hlo[pp][m][ncol] = lb;
      if (LAST && t == TSTEPS - 1) {
        hlast[(size_t)(b0 + m) * HID + ncol] = y;  // f32 handoff to logits
      }
    }
  };

  int j = 0;
  for (;;) {
    step(j, xhA, xlA, xhB, xlB, xvA, xvB);
    if (++j >= jmax) break;
    step(j, xhB, xlB, xhA, xlA, xvB, xvA);
    if (++j >= jmax) break;
  }

  if (!LAST) {  // last step's state was never written back inside the loop
    lds_barrier();
    writeback((jmax - 1) & 1, (jmax - 1) * rate + chain);
  }
}

// logits[b][n] = sum_k h[b][k] * W[k][n] + b[n]
__global__ __launch_bounds__(256) void logits_kernel(
    const float* __restrict__ hlast, const float* __restrict__ W,
    const float* __restrict__ bvec, float* __restrict__ out)
{
  __shared__ float Ws[HID * 10];
  const int tid = threadIdx.x;
  for (int i = tid; i < HID * 10; i += 256) Ws[i] = W[i];
  __syncthreads();
  float acc[10];
#pragma unroll
  for (int n = 0; n < 10; ++n) acc[n] = bvec[n];
  const float* h = hlast + (size_t)tid * HID;
#pragma unroll 4
  for (int k = 0; k < HID; ++k) {
    const float hv = h[k];
#pragma unroll
    for (int n = 0; n < 10; ++n) acc[n] += hv * Ws[k * 10 + n];
  }
#pragma unroll
  for (int n = 0; n < 10; ++n) out[(size_t)tid * 10 + n] = acc[n];
}

extern "C" void kernel_launch(void* const* d_in, const int* in_sizes, int n_in,
                              void* d_out, int out_size, void* d_ws, size_t ws_size,
                              hipStream_t stream) {
  (void)in_sizes; (void)n_in; (void)out_size; (void)ws_size;
  const float* x    = (const float*)d_in[0];   // (256,784,1)
  const float* Wih0 = (const float*)d_in[1];   // (128,1)
  const float* Whh0 = (const float*)d_in[2];   // (128,128)
  const float* bih0 = (const float*)d_in[3];
  const float* bhh0 = (const float*)d_in[4];
  const float* WihA = (const float*)d_in[5];   // (7,128,128)
  const float* WhhA = (const float*)d_in[6];   // (7,128,128)
  const float* bihA = (const float*)d_in[7];   // (7,128)
  const float* bhhA = (const float*)d_in[8];   // (7,128)
  const float* Wout = (const float*)d_in[9];   // (128,10)
  const float* bout = (const float*)d_in[10];  // (10,)
  float* out = (float*)d_out;

  // workspace: 4 bf16 planes (ping-pong x hi/lo) + hlast f32  (~196 MB)
  const size_t planeElems = (size_t)TSTEPS * NBATCH * HID;  // 25,690,112
  unsigned short* b0hi = (unsigned short*)d_ws;
  unsigned short* b0lo = b0hi + planeElems;
  unsigned short* b1hi = b0lo + planeElems;
  unsigned short* b1lo = b1hi + planeElems;
  float* hlast = (float*)(b1lo + planeElems);

  // layer 0 (rate 1, D=1)
  drnn_layer<1, 0><<<dim3(16), dim3(512), 0, stream>>>(
      x, nullptr, nullptr, b0hi, b0lo, nullptr, Wih0, Whh0, bih0, bhh0, 1);

  unsigned short *cur_hi = b0hi, *cur_lo = b0lo, *alt_hi = b1hi, *alt_lo = b1lo;
  for (int i = 0; i < 7; ++i) {
    const int rate = 2 << i;  // 2,4,8,16,32,64,128
    const float* Wih = WihA + (size_t)i * HID * HID;
    const float* Whh = WhhA + (size_t)i * HID * HID;
    const float* bi  = bihA + (size_t)i * HID;
    const float* bh  = bhhA + (size_t)i * HID;
    if (i < 6) {
      drnn_layer<0, 0><<<dim3(16 * rate), dim3(512), 0, stream>>>(
          nullptr, cur_hi, cur_lo, alt_hi, alt_lo, nullptr, Wih, Whh, bi, bh, rate);
      unsigned short* t1 = cur_hi; cur_hi = alt_hi; alt_hi = t1;
      unsigned short* t2 = cur_lo; cur_lo = alt_lo; alt_lo = t2;
    } else {
      // last layer: only t=783 is consumed; f32 handoff, skip plane stores
      drnn_layer<0, 1><<<dim3(16 * rate), dim3(512), 0, stream>>>(
          nullptr, cur_hi, cur_lo, nullptr, nullptr, hlast, Wih, Whh, bi, bh, rate);
    }
  }

  logits_kernel<<<dim3(1), dim3(256), 0, stream>>>(hlast, Wout, bout, out);
}

// Round 4
// 1829.061 us; speedup vs baseline: 1.5383x; 1.4600x over previous
//
#include <hip/hip_runtime.h>

// Dilated RNN forward, MI355X. Round 4:
//  - PRUNED dataflow: only chain c_i of each layer feeds the final logits
//    (c = 0,1,3,7,15,15,15,15), so every layer is 16 WGs; planes store only
//    the timesteps the next layer reads (write-parity rule).
//  - role swap: weights = A operand (registers), h/x = B operand; output
//    D[hidden][batch]. 4 waves/WG, 32 hidden cols/wave -> LDS h-read traffic
//    halves; h-write is one packed ds_write_b64 per tile (uniform banks).
//  - fp32-accurate via bf16 hi/lo split (3 MFMA products), h exchanged as
//    hi/lo bf16 through ping-pong LDS, raw lgkmcnt-only barrier.

typedef __attribute__((ext_vector_type(8))) short bf16x8;
typedef __attribute__((ext_vector_type(4))) float f32x4;
typedef __attribute__((ext_vector_type(2))) unsigned int u32x2;

#define TSTEPS 784
#define NBATCH 256
#define HID 128

__device__ __forceinline__ unsigned short f32_to_bf16(float f) {
  unsigned int u = __builtin_bit_cast(unsigned int, f);
  u = (u + 0x7FFFu + ((u >> 16) & 1u)) >> 16;  // round-to-nearest-even
  return (unsigned short)u;
}
__device__ __forceinline__ float bf16_to_f32(unsigned short s) {
  unsigned int u = ((unsigned int)s) << 16;
  return __builtin_bit_cast(float, u);
}
__device__ __forceinline__ float tanh_fast(float v) {
  float t = __expf(2.0f * v);
  return 1.0f - __fdividef(2.0f, t + 1.0f);
}
// LDS-only barrier: drain own ds ops, sync; global traffic stays in flight.
__device__ __forceinline__ void lds_barrier() {
  asm volatile("s_waitcnt lgkmcnt(0)" ::: "memory");
  __builtin_amdgcn_s_barrier();
  asm volatile("" ::: "memory");
}
__device__ __forceinline__ void load_wfrag(const float* __restrict__ p, bf16x8& hi, bf16x8& lo) {
#pragma unroll
  for (int i = 0; i < 8; ++i) {
    float v = p[i];
    unsigned short h = f32_to_bf16(v);
    float rem = v - bf16_to_f32(h);
    hi[i] = (short)h;
    lo[i] = (short)f32_to_bf16(rem);
  }
}

// One pruned dilated-RNN chain. Grid: 16 WGs x 256 threads (4 waves).
// WG wg: batches [wg*16, wg*16+16). Wave w: hidden-out cols [32w, 32w+32).
// MFMA roles: A = weights (M=hidden-out), B = h/x (N=batch), K = hidden-in.
// Lane conventions (verified triple from R1/R3 passing kernel):
//   A-frag: row = lane&15, k-slot (lane>>4, s) -> k = kb*32 + (lane>>4)*8 + s
//   B-frag: col = lane&15, same k mapping
//   C-frag: value r of lane l -> row (l>>4)*4+r (hidden), col l&15 (batch)
template<int LAYER0, int LAST>
__global__ __launch_bounds__(256, 1) void drnn_layer(
    const float* __restrict__ x0,              // LAYER0: x (B,T) fp32
    const unsigned short* __restrict__ Yin_hi, // else: prev plane [T][B][H]
    const unsigned short* __restrict__ Yin_lo,
    unsigned short* __restrict__ Yout_hi,
    unsigned short* __restrict__ Yout_lo,
    float* __restrict__ hlast,                 // LAST: t=783 output, f32 [B][H]
    const float* __restrict__ Wih,
    const float* __restrict__ Whh,
    const float* __restrict__ bih,
    const float* __restrict__ bhh,
    int rate, int chain, int jmax, int wparity)
{
  // H layout: [batch 16][hidden 128 @pitch 136]; pitch 136 shorts = 68 dwords
  // -> row offset 4 banks: b128 reads and b64 writes are bank-uniform.
  __shared__ __align__(16) unsigned short Hhi[2][16][136];
  __shared__ __align__(16) unsigned short Hlo[2][16][136];

  const int tid  = threadIdx.x;
  const int wave = tid >> 6;      // 0..3
  const int lane = tid & 63;
  const int lrow = lane & 15;     // A row / B col / C col (batch)
  const int lgrp = lane >> 4;     // k-slot group; also C row group
  const int b0   = blockIdx.x << 4;

  // ---- persistent weight A-frags ----
  bf16x8 whhh[2][4], whhl[2][4], wihh[2][4], wihl[2][4];
#pragma unroll
  for (int tl = 0; tl < 2; ++tl) {
    const float* wp = Whh + (size_t)(wave * 32 + tl * 16 + lrow) * HID + lgrp * 8;
#pragma unroll
    for (int kb = 0; kb < 4; ++kb)
      load_wfrag(wp + kb * 32, whhh[tl][kb], whhl[tl][kb]);
  }
  if (!LAYER0) {
#pragma unroll
    for (int tl = 0; tl < 2; ++tl) {
      const float* wp = Wih + (size_t)(wave * 32 + tl * 16 + lrow) * HID + lgrp * 8;
#pragma unroll
      for (int kb = 0; kb < 4; ++kb)
        load_wfrag(wp + kb * 32, wihh[tl][kb], wihl[tl][kb]);
    }
  }
  // bias / layer0-w0 indexed by this lane's C rows: n = 32*wave+16*tl+4*lgrp+r
  f32x4 bias_[2], w0_[2];
#pragma unroll
  for (int tl = 0; tl < 2; ++tl)
#pragma unroll
    for (int r = 0; r < 4; ++r) {
      const int n = wave * 32 + tl * 16 + lgrp * 4 + r;
      bias_[tl][r] = bih[n] + bhh[n];
      w0_[tl][r]   = LAYER0 ? Wih[n] : 0.0f;
    }

  // x double-buffer (B-frags, or scalar for layer 0)
  bf16x8 xhA[4], xlA[4], xhB[4], xlB[4];
  float xvA = 0.f, xvB = 0.f;
  if (LAYER0) {
    xvA = x0[(size_t)(b0 + lrow) * TSTEPS + chain];
  } else {
    const size_t base = ((size_t)chain * NBATCH + b0 + lrow) * HID + lgrp * 8;
#pragma unroll
    for (int kb = 0; kb < 4; ++kb) {
      xhA[kb] = *(const bf16x8*)(Yin_hi + base + kb * 32);
      xlA[kb] = *(const bf16x8*)(Yin_lo + base + kb * 32);
    }
  }

  // coalesced plane write-back of H[rp] (fire-and-forget stores)
  auto writeback = [&](int rp, int tsrc) {
    const int row = tid >> 4, cb = tid & 15;
    const size_t e = ((size_t)tsrc * NBATCH + b0 + row) * HID + cb * 8;
    *(bf16x8*)(Yout_hi + e) = *(const bf16x8*)&Hhi[rp][row][cb * 8];
    *(bf16x8*)(Yout_lo + e) = *(const bf16x8*)&Hlo[rp][row][cb * 8];
  };

  auto step = [&](int j, bf16x8 (&xh_c)[4], bf16x8 (&xl_c)[4],
                  bf16x8 (&xh_n)[4], bf16x8 (&xl_n)[4],
                  float& xv_c, float& xv_n) {
    const int t = j * rate + chain;
    // prefetch x for step j+1 (crosses the barrier; latency hidden)
    if (j + 1 < jmax) {
      const int tn = t + rate;
      if (LAYER0) {
        xv_n = x0[(size_t)(b0 + lrow) * TSTEPS + tn];
      } else {
        const size_t base = ((size_t)tn * NBATCH + b0 + lrow) * HID + lgrp * 8;
#pragma unroll
        for (int kb = 0; kb < 4; ++kb) {
          xh_n[kb] = *(const bf16x8*)(Yin_hi + base + kb * 32);
          xl_n[kb] = *(const bf16x8*)(Yin_lo + base + kb * 32);
        }
      }
    }
    // accumulators: bias folded into c0 init
    f32x4 c0[2], c1[2], c2[2];
#pragma unroll
    for (int tl = 0; tl < 2; ++tl) {
      c0[tl] = bias_[tl];
      c1[tl] = f32x4{0.f, 0.f, 0.f, 0.f};
      c2[tl] = f32x4{0.f, 0.f, 0.f, 0.f};
    }
    if (!LAYER0) {  // xW before the barrier (independent of h)
#pragma unroll
      for (int kb = 0; kb < 4; ++kb)
#pragma unroll
        for (int tl = 0; tl < 2; ++tl) {
          c0[tl] = __builtin_amdgcn_mfma_f32_16x16x32_bf16(wihh[tl][kb], xh_c[kb], c0[tl], 0, 0, 0);
          c1[tl] = __builtin_amdgcn_mfma_f32_16x16x32_bf16(wihl[tl][kb], xh_c[kb], c1[tl], 0, 0, 0);
          c2[tl] = __builtin_amdgcn_mfma_f32_16x16x32_bf16(wihh[tl][kb], xl_c[kb], c2[tl], 0, 0, 0);
        }
    }
    if (j > 0) {
      lds_barrier();  // H[rp] visible; global traffic stays in flight
      const int rp = (j - 1) & 1;
      bf16x8 bh[4], bl[4];
#pragma unroll
      for (int kb = 0; kb < 4; ++kb) {
        bh[kb] = *(const bf16x8*)&Hhi[rp][lrow][kb * 32 + lgrp * 8];
        bl[kb] = *(const bf16x8*)&Hlo[rp][lrow][kb * 32 + lgrp * 8];
      }
      if (!LAST && ((j - 1) & 1) == wparity) writeback(rp, t - rate);
#pragma unroll
      for (int kb = 0; kb < 4; ++kb)
#pragma unroll
        for (int tl = 0; tl < 2; ++tl) {
          c0[tl] = __builtin_amdgcn_mfma_f32_16x16x32_bf16(whhh[tl][kb], bh[kb], c0[tl], 0, 0, 0);
          c1[tl] = __builtin_amdgcn_mfma_f32_16x16x32_bf16(whhl[tl][kb], bh[kb], c1[tl], 0, 0, 0);
          c2[tl] = __builtin_amdgcn_mfma_f32_16x16x32_bf16(whhh[tl][kb], bl[kb], c2[tl], 0, 0, 0);
        }
    }
    const int pp = j & 1;
#pragma unroll
    for (int tl = 0; tl < 2; ++tl) {
      f32x4 yv;
      unsigned short hb[4], lb[4];
#pragma unroll
      for (int r = 0; r < 4; ++r) {
        float v = c0[tl][r] + c1[tl][r] + c2[tl][r];
        if (LAYER0) v += xv_c * w0_[tl][r];
        const float y = tanh_fast(v);
        yv[r] = y;
        hb[r] = f32_to_bf16(y);
        lb[r] = f32_to_bf16(y - bf16_to_f32(hb[r]));
      }
      // lane's 4 values are consecutive hidden idx at fixed batch -> b64 write
      const int nb = wave * 32 + tl * 16 + lgrp * 4;
      u32x2 ph, pl;
      ph[0] = (unsigned)hb[0] | ((unsigned)hb[1] << 16);
      ph[1] = (unsigned)hb[2] | ((unsigned)hb[3] << 16);
      pl[0] = (unsigned)lb[0] | ((unsigned)lb[1] << 16);
      pl[1] = (unsigned)lb[2] | ((unsigned)lb[3] << 16);
      *(u32x2*)&Hhi[pp][lrow][nb] = ph;
      *(u32x2*)&Hlo[pp][lrow][nb] = pl;
      if (LAST && t == TSTEPS - 1)
        *(f32x4*)&hlast[(size_t)(b0 + lrow) * HID + nb] = yv;
    }
  };

  int j = 0;
  for (;;) {
    step(j, xhA, xlA, xhB, xlB, xvA, xvB);
    if (++j >= jmax) break;
    step(j, xhB, xlB, xhA, xlA, xvB, xvA);
    if (++j >= jmax) break;
  }
  if (!LAST && ((jmax - 1) & 1) == wparity) {  // tail state if consumed
    lds_barrier();
    writeback((jmax - 1) & 1, (jmax - 1) * rate + chain);
  }
}

// logits[b][n] = sum_k hlast[b][k] * W[k][n] + b[n]
__global__ __launch_bounds__(256) void logits_kernel(
    const float* __restrict__ hlast, const float* __restrict__ W,
    const float* __restrict__ bvec, float* __restrict__ out)
{
  __shared__ float Ws[HID * 10];
  const int tid = threadIdx.x;
  for (int i = tid; i < HID * 10; i += 256) Ws[i] = W[i];
  __syncthreads();
  float acc[10];
#pragma unroll
  for (int n = 0; n < 10; ++n) acc[n] = bvec[n];
  const float* h = hlast + (size_t)tid * HID;
#pragma unroll 4
  for (int k = 0; k < HID; ++k) {
    const float hv = h[k];
#pragma unroll
    for (int n = 0; n < 10; ++n) acc[n] += hv * Ws[k * 10 + n];
  }
#pragma unroll
  for (int n = 0; n < 10; ++n) out[(size_t)tid * 10 + n] = acc[n];
}

extern "C" void kernel_launch(void* const* d_in, const int* in_sizes, int n_in,
                              void* d_out, int out_size, void* d_ws, size_t ws_size,
                              hipStream_t stream) {
  (void)in_sizes; (void)n_in; (void)out_size; (void)ws_size;
  const float* x    = (const float*)d_in[0];   // (256,784,1)
  const float* Wih0 = (const float*)d_in[1];   // (128,1)
  const float* Whh0 = (const float*)d_in[2];   // (128,128)
  const float* bih0 = (const float*)d_in[3];
  const float* bhh0 = (const float*)d_in[4];
  const float* WihA = (const float*)d_in[5];   // (7,128,128)
  const float* WhhA = (const float*)d_in[6];   // (7,128,128)
  const float* bihA = (const float*)d_in[7];   // (7,128)
  const float* bhhA = (const float*)d_in[8];   // (7,128)
  const float* Wout = (const float*)d_in[9];   // (128,10)
  const float* bout = (const float*)d_in[10];  // (10,)
  float* out = (float*)d_out;

  // workspace: 4 bf16 planes (ping-pong x hi/lo) + hlast f32
  const size_t planeElems = (size_t)TSTEPS * NBATCH * HID;  // 25,690,112
  unsigned short* b0hi = (unsigned short*)d_ws;
  unsigned short* b0lo = b0hi + planeElems;
  unsigned short* b1hi = b0lo + planeElems;
  unsigned short* b1lo = b1hi + planeElems;
  float* hlast = (float*)(b1lo + planeElems);

  // Pruned chains: only chain c_i of each layer reaches the logits.
  //   layer:   L0  L1  L2  L3  L4  L5  L6  L7
  //   rate:     1   2   4   8  16  32  64 128
  //   chain:    0   1   3   7  15  15  15  15
  //   jmax:   784 392 196  98  49  25  13   7
  //   wparity:  1   1   1   1   0   0   0   -   (which j's the next layer reads)
  static const int rates[8]  = {1, 2, 4, 8, 16, 32, 64, 128};
  static const int chains[8] = {0, 1, 3, 7, 15, 15, 15, 15};
  static const int jmaxs[8]  = {784, 392, 196, 98, 49, 25, 13, 7};
  static const int wpars[8]  = {1, 1, 1, 1, 0, 0, 0, 0};

  // layer 0 (rate 1, scalar input)
  drnn_layer<1, 0><<<dim3(16), dim3(256), 0, stream>>>(
      x, nullptr, nullptr, b0hi, b0lo, nullptr, Wih0, Whh0, bih0, bhh0,
      rates[0], chains[0], jmaxs[0], wpars[0]);

  unsigned short *cur_hi = b0hi, *cur_lo = b0lo, *alt_hi = b1hi, *alt_lo = b1lo;
  for (int i = 0; i < 7; ++i) {
    const float* Wih = WihA + (size_t)i * HID * HID;
    const float* Whh = WhhA + (size_t)i * HID * HID;
    const float* bi  = bihA + (size_t)i * HID;
    const float* bh  = bhhA + (size_t)i * HID;
    if (i < 6) {
      drnn_layer<0, 0><<<dim3(16), dim3(256), 0, stream>>>(
          nullptr, cur_hi, cur_lo, alt_hi, alt_lo, nullptr, Wih, Whh, bi, bh,
          rates[i + 1], chains[i + 1], jmaxs[i + 1], wpars[i + 1]);
      unsigned short* t1 = cur_hi; cur_hi = alt_hi; alt_hi = t1;
      unsigned short* t2 = cur_lo; cur_lo = alt_lo; alt_lo = t2;
    } else {
      drnn_layer<0, 1><<<dim3(16), dim3(256), 0, stream>>>(
          nullptr, cur_hi, cur_lo, nullptr, nullptr, hlast, Wih, Whh, bi, bh,
          rates[7], chains[7], jmaxs[7], wpars[7]);
    }
  }

  logits_kernel<<<dim3(1), dim3(256), 0, stream>>>(hlast, Wout, bout, out);
}

// Round 5
// 1353.661 us; speedup vs baseline: 2.0785x; 1.3512x over previous
//
#include <hip/hip_runtime.h>

// Dilated RNN forward, MI355X. Round 5: FUSED cross-layer pipeline.
//  - All 8 pruned chains (R4 dataflow) in ONE kernel: 128 WGs = 8 layers x 16
//    batch-groups, all co-resident (<=256 CUs). Layer i+1 pipelines behind
//    layer i via per-(layer,bg) device-scope flags -> serial depth drops from
//    1564 steps to ~784 + tails.
//  - producer: plane stores -> per-wave vmcnt(0) -> s_barrier -> one RELEASE
//    atomic flag store (buffer_wbl2 covers cross-XCD visibility).
//    consumer: relaxed spin + one ACQUIRE load (buffer_inv; also clears
//    replay-stale L2). Flags zeroed per call via hipMemsetAsync (graph-safe).
//  - per-step math identical to R4 (role-swapped MFMA, bf16 hi/lo split,
//    ping-pong LDS, lgkmcnt-only barrier). Planes slot-compacted (~102 MB).

typedef __attribute__((ext_vector_type(8))) short bf16x8;
typedef __attribute__((ext_vector_type(4))) float f32x4;
typedef __attribute__((ext_vector_type(2))) unsigned int u32x2;

#define TSTEPS 784
#define NBATCH 256
#define HID 128

struct Params {
  const float* x0;
  const float* Wih[8];
  const float* Whh[8];
  const float* bih[8];
  const float* bhh[8];
  unsigned short* phi[8];  // slot-indexed output plane of layer i (i<7)
  unsigned short* plo[8];
  float* hlast;
  int* flags;              // flag (layer i -> i+1, bg) at [ (i*16+bg)*64 ]
  int jmax[8];
  int wpar[8];
};

__device__ __forceinline__ unsigned short f32_to_bf16(float f) {
  unsigned int u = __builtin_bit_cast(unsigned int, f);
  u = (u + 0x7FFFu + ((u >> 16) & 1u)) >> 16;  // RTNE
  return (unsigned short)u;
}
__device__ __forceinline__ float bf16_to_f32(unsigned short s) {
  unsigned int u = ((unsigned int)s) << 16;
  return __builtin_bit_cast(float, u);
}
__device__ __forceinline__ float tanh_fast(float v) {
  float t = __expf(2.0f * v);
  return 1.0f - __fdividef(2.0f, t + 1.0f);
}
// LDS-only barrier: drain own ds ops, sync; global traffic stays in flight.
__device__ __forceinline__ void lds_barrier() {
  asm volatile("s_waitcnt lgkmcnt(0)" ::: "memory");
  __builtin_amdgcn_s_barrier();
  asm volatile("" ::: "memory");
}
__device__ __forceinline__ void wait_flag(int* f, int need) {
  while (__hip_atomic_load(f, __ATOMIC_RELAXED, __HIP_MEMORY_SCOPE_AGENT) < need)
    __builtin_amdgcn_s_sleep(2);
  (void)__hip_atomic_load(f, __ATOMIC_ACQUIRE, __HIP_MEMORY_SCOPE_AGENT);
}
__device__ __forceinline__ void load_wfrag(const float* __restrict__ p, bf16x8& hi, bf16x8& lo) {
#pragma unroll
  for (int i = 0; i < 8; ++i) {
    float v = p[i];
    unsigned short h = f32_to_bf16(v);
    float rem = v - bf16_to_f32(h);
    hi[i] = (short)h;
    lo[i] = (short)f32_to_bf16(rem);
  }
}

// Fused pipeline. Grid: 128 WGs x 256 threads. WG -> (layer, batch-group).
// Per-WG body identical to R4's drnn_layer (verified lane-convention triple).
__global__ __launch_bounds__(256, 1) void drnn_fused(Params P) {
  __shared__ __align__(16) unsigned short Hhi[2][16][136];
  __shared__ __align__(16) unsigned short Hlo[2][16][136];

  const int layer  = blockIdx.x >> 4;
  const int bg     = blockIdx.x & 15;
  const bool isL0   = (layer == 0);
  const bool isLast = (layer == 7);
  const int jmax = P.jmax[layer];
  const int wpar = P.wpar[layer];
  const float* __restrict__ Wih = P.Wih[layer];
  const float* __restrict__ Whh = P.Whh[layer];
  const float* __restrict__ bih = P.bih[layer];
  const float* __restrict__ bhh = P.bhh[layer];
  const float* __restrict__ x0  = P.x0;
  const unsigned short* __restrict__ Yin_hi = isL0 ? nullptr : P.phi[layer - 1];
  const unsigned short* __restrict__ Yin_lo = isL0 ? nullptr : P.plo[layer - 1];
  unsigned short* __restrict__ Yout_hi = isLast ? nullptr : P.phi[layer];
  unsigned short* __restrict__ Yout_lo = isLast ? nullptr : P.plo[layer];
  int* fin  = isL0 ? nullptr : P.flags + 64 * ((layer - 1) * 16 + bg);
  int* fout = isLast ? nullptr : P.flags + 64 * (layer * 16 + bg);

  const int tid  = threadIdx.x;
  const int wave = tid >> 6;      // 0..3
  const int lane = tid & 63;
  const int lrow = lane & 15;     // A row / B col / C col (batch)
  const int lgrp = lane >> 4;     // k-slot group; C row group
  const int b0   = bg << 4;

  // ---- persistent weight A-frags ----
  bf16x8 whhh[2][4], whhl[2][4], wihh[2][4], wihl[2][4];
#pragma unroll
  for (int tl = 0; tl < 2; ++tl) {
    const float* wp = Whh + (size_t)(wave * 32 + tl * 16 + lrow) * HID + lgrp * 8;
#pragma unroll
    for (int kb = 0; kb < 4; ++kb)
      load_wfrag(wp + kb * 32, whhh[tl][kb], whhl[tl][kb]);
  }
  if (!isL0) {
#pragma unroll
    for (int tl = 0; tl < 2; ++tl) {
      const float* wp = Wih + (size_t)(wave * 32 + tl * 16 + lrow) * HID + lgrp * 8;
#pragma unroll
      for (int kb = 0; kb < 4; ++kb)
        load_wfrag(wp + kb * 32, wihh[tl][kb], wihl[tl][kb]);
    }
  }
  f32x4 bias_[2], w0_[2];
#pragma unroll
  for (int tl = 0; tl < 2; ++tl)
#pragma unroll
    for (int r = 0; r < 4; ++r) {
      const int n = wave * 32 + tl * 16 + lgrp * 4 + r;
      bias_[tl][r] = bih[n] + bhh[n];
      w0_[tl][r]   = isL0 ? Wih[n] : 0.0f;
    }

  // x double-buffer (slot-indexed input planes; L0 reads raw x, t = j)
  bf16x8 xhA[4], xlA[4], xhB[4], xlB[4];
  float xvA = 0.f, xvB = 0.f;
  if (isL0) {
    xvA = x0[(size_t)(b0 + lrow) * TSTEPS + 0];
  } else {
    wait_flag(fin, 1);
    const size_t base = ((size_t)0 * NBATCH + b0 + lrow) * HID + lgrp * 8;
#pragma unroll
    for (int kb = 0; kb < 4; ++kb) {
      xhA[kb] = *(const bf16x8*)(Yin_hi + base + kb * 32);
      xlA[kb] = *(const bf16x8*)(Yin_lo + base + kb * 32);
    }
  }

  // coalesced plane write-back of H[rp] into consumer slot
  auto writeback = [&](int rp, int slot) {
    const int row = tid >> 4, cb = tid & 15;
    const size_t e = ((size_t)slot * NBATCH + b0 + row) * HID + cb * 8;
    *(bf16x8*)(Yout_hi + e) = *(const bf16x8*)&Hhi[rp][row][cb * 8];
    *(bf16x8*)(Yout_lo + e) = *(const bf16x8*)&Hlo[rp][row][cb * 8];
  };
  // make this WG's plane stores device-visible, then signal
  auto signal = [&](int slot) {
    asm volatile("s_waitcnt vmcnt(0)" ::: "memory");
    __builtin_amdgcn_s_barrier();
    if (tid == 0)
      __hip_atomic_store(fout, slot + 1, __ATOMIC_RELEASE, __HIP_MEMORY_SCOPE_AGENT);
  };

  auto step = [&](int j, bf16x8 (&xh_c)[4], bf16x8 (&xl_c)[4],
                  bf16x8 (&xh_n)[4], bf16x8 (&xl_n)[4],
                  float& xv_c, float& xv_n) -> int {
    int wbslot = -1;
    // prefetch input for step j+1 (gated by producer flag for slot j+1)
    if (j + 1 < jmax) {
      if (isL0) {
        xv_n = x0[(size_t)(b0 + lrow) * TSTEPS + (j + 1)];
      } else {
        wait_flag(fin, j + 2);
        const size_t base = ((size_t)(j + 1) * NBATCH + b0 + lrow) * HID + lgrp * 8;
#pragma unroll
        for (int kb = 0; kb < 4; ++kb) {
          xh_n[kb] = *(const bf16x8*)(Yin_hi + base + kb * 32);
          xl_n[kb] = *(const bf16x8*)(Yin_lo + base + kb * 32);
        }
      }
    }
    f32x4 c0[2], c1[2], c2[2];
#pragma unroll
    for (int tl = 0; tl < 2; ++tl) {
      c0[tl] = bias_[tl];
      c1[tl] = f32x4{0.f, 0.f, 0.f, 0.f};
      c2[tl] = f32x4{0.f, 0.f, 0.f, 0.f};
    }
    if (!isL0) {  // xW before the barrier (independent of h)
#pragma unroll
      for (int kb = 0; kb < 4; ++kb)
#pragma unroll
        for (int tl = 0; tl < 2; ++tl) {
          c0[tl] = __builtin_amdgcn_mfma_f32_16x16x32_bf16(wihh[tl][kb], xh_c[kb], c0[tl], 0, 0, 0);
          c1[tl] = __builtin_amdgcn_mfma_f32_16x16x32_bf16(wihl[tl][kb], xh_c[kb], c1[tl], 0, 0, 0);
          c2[tl] = __builtin_amdgcn_mfma_f32_16x16x32_bf16(wihh[tl][kb], xl_c[kb], c2[tl], 0, 0, 0);
        }
    }
    if (j > 0) {
      lds_barrier();  // H[rp] visible; global traffic stays in flight
      const int rp = (j - 1) & 1;
      bf16x8 bh[4], bl[4];
#pragma unroll
      for (int kb = 0; kb < 4; ++kb) {
        bh[kb] = *(const bf16x8*)&Hhi[rp][lrow][kb * 32 + lgrp * 8];
        bl[kb] = *(const bf16x8*)&Hlo[rp][lrow][kb * 32 + lgrp * 8];
      }
      if (!isLast && ((j - 1) & 1) == wpar) {
        wbslot = (j - 1 - wpar) >> 1;
        writeback(rp, wbslot);
      }
#pragma unroll
      for (int kb = 0; kb < 4; ++kb)
#pragma unroll
        for (int tl = 0; tl < 2; ++tl) {
          c0[tl] = __builtin_amdgcn_mfma_f32_16x16x32_bf16(whhh[tl][kb], bh[kb], c0[tl], 0, 0, 0);
          c1[tl] = __builtin_amdgcn_mfma_f32_16x16x32_bf16(whhl[tl][kb], bh[kb], c1[tl], 0, 0, 0);
          c2[tl] = __builtin_amdgcn_mfma_f32_16x16x32_bf16(whhh[tl][kb], bl[kb], c2[tl], 0, 0, 0);
        }
    }
    const int pp = j & 1;
#pragma unroll
    for (int tl = 0; tl < 2; ++tl) {
      f32x4 yv;
      unsigned short hb[4], lb[4];
#pragma unroll
      for (int r = 0; r < 4; ++r) {
        float v = c0[tl][r] + c1[tl][r] + c2[tl][r];
        if (isL0) v += xv_c * w0_[tl][r];
        const float y = tanh_fast(v);
        yv[r] = y;
        hb[r] = f32_to_bf16(y);
        lb[r] = f32_to_bf16(y - bf16_to_f32(hb[r]));
      }
      const int nb = wave * 32 + tl * 16 + lgrp * 4;
      u32x2 ph, pl;
      ph[0] = (unsigned)hb[0] | ((unsigned)hb[1] << 16);
      ph[1] = (unsigned)hb[2] | ((unsigned)hb[3] << 16);
      pl[0] = (unsigned)lb[0] | ((unsigned)lb[1] << 16);
      pl[1] = (unsigned)lb[2] | ((unsigned)lb[3] << 16);
      *(u32x2*)&Hhi[pp][lrow][nb] = ph;
      *(u32x2*)&Hlo[pp][lrow][nb] = pl;
      if (isLast && j == jmax - 1)
        *(f32x4*)&P.hlast[(size_t)(b0 + lrow) * HID + nb] = yv;
    }
    return wbslot;
  };

  int j = 0;
  for (;;) {
    int s = step(j, xhA, xlA, xhB, xlB, xvA, xvB);
    if (s >= 0) signal(s);
    if (++j >= jmax) break;
    s = step(j, xhB, xlB, xhA, xlA, xvB, xvA);
    if (s >= 0) signal(s);
    if (++j >= jmax) break;
  }
  if (!isLast && ((jmax - 1) & 1) == wpar) {  // final state -> last slot
    lds_barrier();
    const int slot = (jmax - 1 - wpar) >> 1;
    writeback((jmax - 1) & 1, slot);
    signal(slot);
  }
}

// logits[b][n] = sum_k hlast[b][k] * W[k][n] + b[n]
__global__ __launch_bounds__(256) void logits_kernel(
    const float* __restrict__ hlast, const float* __restrict__ W,
    const float* __restrict__ bvec, float* __restrict__ out)
{
  __shared__ float Ws[HID * 10];
  const int tid = threadIdx.x;
  for (int i = tid; i < HID * 10; i += 256) Ws[i] = W[i];
  __syncthreads();
  float acc[10];
#pragma unroll
  for (int n = 0; n < 10; ++n) acc[n] = bvec[n];
  const float* h = hlast + (size_t)tid * HID;
#pragma unroll 4
  for (int k = 0; k < HID; ++k) {
    const float hv = h[k];
#pragma unroll
    for (int n = 0; n < 10; ++n) acc[n] += hv * Ws[k * 10 + n];
  }
#pragma unroll
  for (int n = 0; n < 10; ++n) out[(size_t)tid * 10 + n] = acc[n];
}

extern "C" void kernel_launch(void* const* d_in, const int* in_sizes, int n_in,
                              void* d_out, int out_size, void* d_ws, size_t ws_size,
                              hipStream_t stream) {
  (void)in_sizes; (void)n_in; (void)out_size; (void)ws_size;
  const float* x    = (const float*)d_in[0];   // (256,784,1)
  const float* Wih0 = (const float*)d_in[1];   // (128,1)
  const float* Whh0 = (const float*)d_in[2];   // (128,128)
  const float* bih0 = (const float*)d_in[3];
  const float* bhh0 = (const float*)d_in[4];
  const float* WihA = (const float*)d_in[5];   // (7,128,128)
  const float* WhhA = (const float*)d_in[6];   // (7,128,128)
  const float* bihA = (const float*)d_in[7];   // (7,128)
  const float* bhhA = (const float*)d_in[8];   // (7,128)
  const float* Wout = (const float*)d_in[9];   // (128,10)
  const float* bout = (const float*)d_in[10];  // (10,)
  float* out = (float*)d_out;

  // Pruned chains (R4 dataflow): chain c = 0,1,3,7,15,15,15,15
  static const int jmaxs[8] = {784, 392, 196, 98, 49, 25, 13, 7};
  static const int wpars[8] = {1, 1, 1, 1, 0, 0, 0, 0};

  Params P;
  P.x0 = x;
  P.Wih[0] = Wih0; P.Whh[0] = Whh0; P.bih[0] = bih0; P.bhh[0] = bhh0;
  for (int i = 0; i < 7; ++i) {
    P.Wih[i + 1] = WihA + (size_t)i * HID * HID;
    P.Whh[i + 1] = WhhA + (size_t)i * HID * HID;
    P.bih[i + 1] = bihA + (size_t)i * HID;
    P.bhh[i + 1] = bhhA + (size_t)i * HID;
  }
  for (int i = 0; i < 8; ++i) { P.jmax[i] = jmaxs[i]; P.wpar[i] = wpars[i]; }

  // workspace: per-layer slot-compacted hi/lo planes (~102 MB) + hlast + flags
  unsigned short* wsp = (unsigned short*)d_ws;
  size_t off = 0;
  for (int i = 0; i < 7; ++i) {
    const size_t slots = (size_t)jmaxs[i + 1] * NBATCH * HID;
    P.phi[i] = wsp + off; off += slots;
    P.plo[i] = wsp + off; off += slots;
  }
  P.phi[7] = nullptr; P.plo[7] = nullptr;
  P.hlast = (float*)(wsp + off); off += (size_t)NBATCH * HID * 2;  // f32 = 2 shorts
  int* flags = (int*)(wsp + off);
  P.flags = flags;

  hipMemsetAsync(flags, 0, 7 * 16 * 64 * sizeof(int), stream);
  drnn_fused<<<dim3(128), dim3(256), 0, stream>>>(P);
  logits_kernel<<<dim3(1), dim3(256), 0, stream>>>(P.hlast, Wout, bout, out);
}

// Round 6
// 985.910 us; speedup vs baseline: 2.8538x; 1.3730x over previous
//
#include <hip/hip_runtime.h>

// Dilated RNN forward, MI355X. Round 6: fused pipeline + amortized handshake.
//  - R5 structure: 128 WGs = 8 pruned layers x 16 batch-groups, co-resident;
//    layer i+1 pipelines behind layer i (serial depth ~784, not 1564).
//  - NEW: batched DELAYED signaling — producer signals once per SIGB slots,
//    BEFORE writing the next slot (so the release's vmcnt(0) drains only old,
//    long-complete stores); consumer caches the acquired flag (one
//    buffer_inv per batch instead of per step).
//  - NEW: epilogue diet — truncation hi/lo split + v_perm_b32 packing,
//    tanh via exp2+rcp (5 ops). Split stays exact: rem = y - hi is exact,
//    lo covers to 2^-16 relative.

typedef __attribute__((ext_vector_type(8))) short bf16x8;
typedef __attribute__((ext_vector_type(4))) float f32x4;
typedef __attribute__((ext_vector_type(2))) unsigned int u32x2;

#define TSTEPS 784
#define NBATCH 256
#define HID 128

struct Params {
  const float* x0;
  const float* Wih[8];
  const float* Whh[8];
  const float* bih[8];
  const float* bhh[8];
  unsigned short* phi[8];  // slot-indexed output plane of layer i (i<7)
  unsigned short* plo[8];
  float* hlast;
  int* flags;              // flag (layer i -> i+1, bg) at [(i*16+bg)*64]
  int jmax[8];
  int wpar[8];
  int sigb[8];             // producer signal batch (slots)
};

__device__ __forceinline__ unsigned short f32_to_bf16(float f) {
  unsigned int u = __builtin_bit_cast(unsigned int, f);
  u = (u + 0x7FFFu + ((u >> 16) & 1u)) >> 16;  // RTNE (setup path only)
  return (unsigned short)u;
}
__device__ __forceinline__ float bf16_to_f32(unsigned short s) {
  unsigned int u = ((unsigned int)s) << 16;
  return __builtin_bit_cast(float, u);
}
// LDS-only barrier: drain own ds ops, sync; global traffic stays in flight.
__device__ __forceinline__ void lds_barrier() {
  asm volatile("s_waitcnt lgkmcnt(0)" ::: "memory");
  __builtin_amdgcn_s_barrier();
  asm volatile("" ::: "memory");
}
__device__ __forceinline__ void load_wfrag(const float* __restrict__ p, bf16x8& hi, bf16x8& lo) {
#pragma unroll
  for (int i = 0; i < 8; ++i) {
    float v = p[i];
    unsigned short h = f32_to_bf16(v);
    float rem = v - bf16_to_f32(h);
    hi[i] = (short)h;
    lo[i] = (short)f32_to_bf16(rem);
  }
}

// Fused pipeline. Grid: 128 WGs x 256 threads. WG -> (layer, batch-group).
// Lane-convention triple verified in R1-R5 (A row=l&15; B col=l&15;
// k = kb*32+(l>>4)*8+s; C: value r of lane l -> row (l>>4)*4+r, col l&15).
__global__ __launch_bounds__(256, 1) void drnn_fused(Params P) {
  __shared__ __align__(16) unsigned short Hhi[2][16][136];
  __shared__ __align__(16) unsigned short Hlo[2][16][136];

  const int layer  = blockIdx.x >> 4;
  const int bg     = blockIdx.x & 15;
  const bool isL0   = (layer == 0);
  const bool isLast = (layer == 7);
  const int jmax = P.jmax[layer];
  const int wpar = P.wpar[layer];
  const int SIGB = P.sigb[layer];
  const float* __restrict__ Wih = P.Wih[layer];
  const float* __restrict__ Whh = P.Whh[layer];
  const float* __restrict__ bih = P.bih[layer];
  const float* __restrict__ bhh = P.bhh[layer];
  const float* __restrict__ x0  = P.x0;
  const unsigned short* __restrict__ Yin_hi = isL0 ? nullptr : P.phi[layer - 1];
  const unsigned short* __restrict__ Yin_lo = isL0 ? nullptr : P.plo[layer - 1];
  unsigned short* __restrict__ Yout_hi = isLast ? nullptr : P.phi[layer];
  unsigned short* __restrict__ Yout_lo = isLast ? nullptr : P.plo[layer];
  int* fin  = isL0 ? nullptr : P.flags + 64 * ((layer - 1) * 16 + bg);
  int* fout = isLast ? nullptr : P.flags + 64 * (layer * 16 + bg);

  const int tid  = threadIdx.x;
  const int wave = tid >> 6;      // 0..3
  const int lane = tid & 63;
  const int lrow = lane & 15;     // A row / B col / C col (batch)
  const int lgrp = lane >> 4;     // k-slot group; C row group
  const int b0   = bg << 4;

  // consumer flag cache: acquire (buffer_inv) only when crossing a batch
  int seen = 0;
  auto wait_in = [&](int need) {
    if (seen >= need) return;
    while (__hip_atomic_load(fin, __ATOMIC_RELAXED, __HIP_MEMORY_SCOPE_AGENT) < need)
      __builtin_amdgcn_s_sleep(2);
    seen = __hip_atomic_load(fin, __ATOMIC_ACQUIRE, __HIP_MEMORY_SCOPE_AGENT);
  };

  // ---- persistent weight A-frags ----
  bf16x8 whhh[2][4], whhl[2][4], wihh[2][4], wihl[2][4];
#pragma unroll
  for (int tl = 0; tl < 2; ++tl) {
    const float* wp = Whh + (size_t)(wave * 32 + tl * 16 + lrow) * HID + lgrp * 8;
#pragma unroll
    for (int kb = 0; kb < 4; ++kb)
      load_wfrag(wp + kb * 32, whhh[tl][kb], whhl[tl][kb]);
  }
  if (!isL0) {
#pragma unroll
    for (int tl = 0; tl < 2; ++tl) {
      const float* wp = Wih + (size_t)(wave * 32 + tl * 16 + lrow) * HID + lgrp * 8;
#pragma unroll
      for (int kb = 0; kb < 4; ++kb)
        load_wfrag(wp + kb * 32, wihh[tl][kb], wihl[tl][kb]);
    }
  }
  f32x4 bias_[2], w0_[2];
#pragma unroll
  for (int tl = 0; tl < 2; ++tl)
#pragma unroll
    for (int r = 0; r < 4; ++r) {
      const int n = wave * 32 + tl * 16 + lgrp * 4 + r;
      bias_[tl][r] = bih[n] + bhh[n];
      w0_[tl][r]   = isL0 ? Wih[n] : 0.0f;
    }

  // x double-buffer (slot-indexed input planes; L0 reads raw x, t = j)
  bf16x8 xhA[4], xlA[4], xhB[4], xlB[4];
  float xvA = 0.f, xvB = 0.f;
  if (isL0) {
    xvA = x0[(size_t)(b0 + lrow) * TSTEPS + 0];
  } else {
    wait_in(1);
    const size_t base = ((size_t)b0 + lrow) * HID + lgrp * 8;
#pragma unroll
    for (int kb = 0; kb < 4; ++kb) {
      xhA[kb] = *(const bf16x8*)(Yin_hi + base + kb * 32);
      xlA[kb] = *(const bf16x8*)(Yin_lo + base + kb * 32);
    }
  }

  // coalesced plane write-back of H[rp] into consumer slot
  auto writeback = [&](int rp, int slot) {
    const int row = tid >> 4, cb = tid & 15;
    const size_t e = ((size_t)slot * NBATCH + b0 + row) * HID + cb * 8;
    *(bf16x8*)(Yout_hi + e) = *(const bf16x8*)&Hhi[rp][row][cb * 8];
    *(bf16x8*)(Yout_lo + e) = *(const bf16x8*)&Hlo[rp][row][cb * 8];
  };

  int next_sig = SIGB;  // first in-loop signal when about to write slot SIGB

  auto step = [&](int j, bf16x8 (&xh_c)[4], bf16x8 (&xl_c)[4],
                  bf16x8 (&xh_n)[4], bf16x8 (&xl_n)[4],
                  float& xv_c, float& xv_n) {
    // prefetch input for step j+1 (gated by producer flag for slot j+1)
    if (j + 1 < jmax) {
      if (isL0) {
        xv_n = x0[(size_t)(b0 + lrow) * TSTEPS + (j + 1)];
      } else {
        wait_in(j + 2);
        const size_t base = ((size_t)(j + 1) * NBATCH + b0 + lrow) * HID + lgrp * 8;
#pragma unroll
        for (int kb = 0; kb < 4; ++kb) {
          xh_n[kb] = *(const bf16x8*)(Yin_hi + base + kb * 32);
          xl_n[kb] = *(const bf16x8*)(Yin_lo + base + kb * 32);
        }
      }
    }
    f32x4 c0[2], c1[2], c2[2];
#pragma unroll
    for (int tl = 0; tl < 2; ++tl) {
      c0[tl] = bias_[tl];
      c1[tl] = f32x4{0.f, 0.f, 0.f, 0.f};
      c2[tl] = f32x4{0.f, 0.f, 0.f, 0.f};
    }
    if (!isL0) {  // xW before the barrier (independent of h)
#pragma unroll
      for (int kb = 0; kb < 4; ++kb)
#pragma unroll
        for (int tl = 0; tl < 2; ++tl) {
          c0[tl] = __builtin_amdgcn_mfma_f32_16x16x32_bf16(wihh[tl][kb], xh_c[kb], c0[tl], 0, 0, 0);
          c1[tl] = __builtin_amdgcn_mfma_f32_16x16x32_bf16(wihl[tl][kb], xh_c[kb], c1[tl], 0, 0, 0);
          c2[tl] = __builtin_amdgcn_mfma_f32_16x16x32_bf16(wihh[tl][kb], xl_c[kb], c2[tl], 0, 0, 0);
        }
    }
    if (j > 0) {
      lds_barrier();  // H[rp] visible; global traffic stays in flight
      const int rp = (j - 1) & 1;
      bf16x8 bh[4], bl[4];
#pragma unroll
      for (int kb = 0; kb < 4; ++kb) {
        bh[kb] = *(const bf16x8*)&Hhi[rp][lrow][kb * 32 + lgrp * 8];
        bl[kb] = *(const bf16x8*)&Hlo[rp][lrow][kb * 32 + lgrp * 8];
      }
      if (!isLast && ((j - 1) & 1) == wpar) {
        const int wbslot = (j - 1 - wpar) >> 1;
        if (wbslot == next_sig) {
          // delayed batch signal: covers slots [0, wbslot) — their stores
          // were issued >=2 steps ago, so this vmcnt(0) is nearly free.
          asm volatile("s_waitcnt vmcnt(0)" ::: "memory");
          __builtin_amdgcn_s_barrier();
          if (tid == 0)
            __hip_atomic_store(fout, wbslot, __ATOMIC_RELEASE, __HIP_MEMORY_SCOPE_AGENT);
          next_sig += SIGB;
        }
        writeback(rp, wbslot);
      }
#pragma unroll
      for (int kb = 0; kb < 4; ++kb)
#pragma unroll
        for (int tl = 0; tl < 2; ++tl) {
          c0[tl] = __builtin_amdgcn_mfma_f32_16x16x32_bf16(whhh[tl][kb], bh[kb], c0[tl], 0, 0, 0);
          c1[tl] = __builtin_amdgcn_mfma_f32_16x16x32_bf16(whhl[tl][kb], bh[kb], c1[tl], 0, 0, 0);
          c2[tl] = __builtin_amdgcn_mfma_f32_16x16x32_bf16(whhh[tl][kb], bl[kb], c2[tl], 0, 0, 0);
        }
    }
    const int pp = j & 1;
#pragma unroll
    for (int tl = 0; tl < 2; ++tl) {
      float y[4];
      f32x4 yv;
#pragma unroll
      for (int r = 0; r < 4; ++r) {
        float v = c0[tl][r] + c1[tl][r] + c2[tl][r];
        if (isL0) v = __builtin_fmaf(xv_c, w0_[tl][r], v);
        // tanh(v) = 1 - 2/(exp2(v*2log2e)+1)
        float t  = __builtin_amdgcn_exp2f(v * 2.885390081777927f);
        float rc = __builtin_amdgcn_rcpf(t + 1.0f);
        y[r] = __builtin_fmaf(-2.0f, rc, 1.0f);
        yv[r] = y[r];
      }
      // truncation hi/lo split: hi = y & 0xffff0000 (exact rem), packed
      // with v_perm_b32 (one op per pair; sel 0x07060302 = high16s)
      float rem[4];
#pragma unroll
      for (int r = 0; r < 4; ++r) {
        float hf = __builtin_bit_cast(float,
            __builtin_bit_cast(unsigned int, y[r]) & 0xffff0000u);
        rem[r] = y[r] - hf;
      }
      u32x2 ph, pl;
      ph[0] = __builtin_amdgcn_perm(__builtin_bit_cast(unsigned int, y[1]),
                                    __builtin_bit_cast(unsigned int, y[0]), 0x07060302u);
      ph[1] = __builtin_amdgcn_perm(__builtin_bit_cast(unsigned int, y[3]),
                                    __builtin_bit_cast(unsigned int, y[2]), 0x07060302u);
      pl[0] = __builtin_amdgcn_perm(__builtin_bit_cast(unsigned int, rem[1]),
                                    __builtin_bit_cast(unsigned int, rem[0]), 0x07060302u);
      pl[1] = __builtin_amdgcn_perm(__builtin_bit_cast(unsigned int, rem[3]),
                                    __builtin_bit_cast(unsigned int, rem[2]), 0x07060302u);
      const int nb = wave * 32 + tl * 16 + lgrp * 4;
      *(u32x2*)&Hhi[pp][lrow][nb] = ph;
      *(u32x2*)&Hlo[pp][lrow][nb] = pl;
      if (isLast && j == jmax - 1)
        *(f32x4*)&P.hlast[(size_t)(b0 + lrow) * HID + nb] = yv;
    }
  };

  int j = 0;
  for (;;) {
    step(j, xhA, xlA, xhB, xlB, xvA, xvB);
    if (++j >= jmax) break;
    step(j, xhB, xlB, xhA, xlA, xvB, xvA);
    if (++j >= jmax) break;
  }

  if (!isLast) {
    if (((jmax - 1) & 1) == wpar) {  // last step's state, if consumed
      lds_barrier();
      writeback((jmax - 1) & 1, (jmax - 1 - wpar) >> 1);
    }
    // final signal: all slots ready (full drain)
    asm volatile("s_waitcnt vmcnt(0)" ::: "memory");
    __builtin_amdgcn_s_barrier();
    if (tid == 0)
      __hip_atomic_store(fout, ((jmax - 1 - wpar) >> 1) + 1,
                         __ATOMIC_RELEASE, __HIP_MEMORY_SCOPE_AGENT);
  }
}

// logits[b][n] = sum_k hlast[b][k] * W[k][n] + b[n]
__global__ __launch_bounds__(256) void logits_kernel(
    const float* __restrict__ hlast, const float* __restrict__ W,
    const float* __restrict__ bvec, float* __restrict__ out)
{
  __shared__ float Ws[HID * 10];
  const int tid = threadIdx.x;
  for (int i = tid; i < HID * 10; i += 256) Ws[i] = W[i];
  __syncthreads();
  float acc[10];
#pragma unroll
  for (int n = 0; n < 10; ++n) acc[n] = bvec[n];
  const float* h = hlast + (size_t)tid * HID;
#pragma unroll 4
  for (int k = 0; k < HID; ++k) {
    const float hv = h[k];
#pragma unroll
    for (int n = 0; n < 10; ++n) acc[n] += hv * Ws[k * 10 + n];
  }
#pragma unroll
  for (int n = 0; n < 10; ++n) out[(size_t)tid * 10 + n] = acc[n];
}

extern "C" void kernel_launch(void* const* d_in, const int* in_sizes, int n_in,
                              void* d_out, int out_size, void* d_ws, size_t ws_size,
                              hipStream_t stream) {
  (void)in_sizes; (void)n_in; (void)out_size; (void)ws_size;
  const float* x    = (const float*)d_in[0];   // (256,784,1)
  const float* Wih0 = (const float*)d_in[1];   // (128,1)
  const float* Whh0 = (const float*)d_in[2];   // (128,128)
  const float* bih0 = (const float*)d_in[3];
  const float* bhh0 = (const float*)d_in[4];
  const float* WihA = (const float*)d_in[5];   // (7,128,128)
  const float* WhhA = (const float*)d_in[6];   // (7,128,128)
  const float* bihA = (const float*)d_in[7];   // (7,128)
  const float* bhhA = (const float*)d_in[8];   // (7,128)
  const float* Wout = (const float*)d_in[9];   // (128,10)
  const float* bout = (const float*)d_in[10];  // (10,)
  float* out = (float*)d_out;

  // Pruned chains (R4 dataflow): chain c = 0,1,3,7,15,15,15,15
  static const int jmaxs[8] = {784, 392, 196, 98, 49, 25, 13, 7};
  static const int wpars[8] = {1, 1, 1, 1, 0, 0, 0, 0};
  static const int sigbs[8] = {8, 8, 8, 8, 4, 2, 2, 0};

  Params P;
  P.x0 = x;
  P.Wih[0] = Wih0; P.Whh[0] = Whh0; P.bih[0] = bih0; P.bhh[0] = bhh0;
  for (int i = 0; i < 7; ++i) {
    P.Wih[i + 1] = WihA + (size_t)i * HID * HID;
    P.Whh[i + 1] = WhhA + (size_t)i * HID * HID;
    P.bih[i + 1] = bihA + (size_t)i * HID;
    P.bhh[i + 1] = bhhA + (size_t)i * HID;
  }
  for (int i = 0; i < 8; ++i) {
    P.jmax[i] = jmaxs[i]; P.wpar[i] = wpars[i]; P.sigb[i] = sigbs[i];
  }

  // workspace: per-layer slot-compacted hi/lo planes (~102 MB) + hlast + flags
  unsigned short* wsp = (unsigned short*)d_ws;
  size_t off = 0;
  for (int i = 0; i < 7; ++i) {
    const size_t slots = (size_t)jmaxs[i + 1] * NBATCH * HID;
    P.phi[i] = wsp + off; off += slots;
    P.plo[i] = wsp + off; off += slots;
  }
  P.phi[7] = nullptr; P.plo[7] = nullptr;
  P.hlast = (float*)(wsp + off); off += (size_t)NBATCH * HID * 2;  // f32 = 2 shorts
  int* flags = (int*)(wsp + off);
  P.flags = flags;

  hipMemsetAsync(flags, 0, 7 * 16 * 64 * sizeof(int), stream);
  drnn_fused<<<dim3(128), dim3(256), 0, stream>>>(P);
  logits_kernel<<<dim3(1), dim3(256), 0, stream>>>(P.hlast, Wout, bout, out);
}

// Round 7
// 970.758 us; speedup vs baseline: 2.8983x; 1.0156x over previous
//
#include <hip/hip_runtime.h>

// Dilated RNN forward, MI355X. Round 7: fused pipeline, CU-exclusive WGs.
//  - R6 structure: 128 WGs = 8 pruned layers x 16 batch-groups, pipelined via
//    batched delayed release/acquire flags (serial depth ~784, not 1564).
//  - NEW: 84KB dynamic LDS per WG -> two WGs can never share a CU (2x84 >
//    160KB). Removes LDS-BW / trans-unit / VALU co-packing contention.
//  - NEW: L0 preloads its x slice (16x784 f32, pitch 788 -> 2-way-free banks)
//    into the spare LDS; L0 main loop has ZERO global loads.
//  - NEW: running-pointer strength reduction for plane prefetch + writeback.

typedef __attribute__((ext_vector_type(8))) short bf16x8;
typedef __attribute__((ext_vector_type(4))) float f32x4;
typedef __attribute__((ext_vector_type(2))) unsigned int u32x2;

#define TSTEPS 784
#define NBATCH 256
#define HID 128
#define SLOT_ELEMS (NBATCH * HID)     // shorts per plane slot (32768)
#define XPITCH 788                    // f32 pitch for L0 x slab (2-way banks)
#define DYN_LDS 86016                 // 84KB -> forces 1 WG/CU (2x84 > 160KB)

struct Params {
  const float* x0;
  const float* Wih[8];
  const float* Whh[8];
  const float* bih[8];
  const float* bhh[8];
  unsigned short* phi[8];  // slot-indexed output plane of layer i (i<7)
  unsigned short* plo[8];
  float* hlast;
  int* flags;              // flag (layer i -> i+1, bg) at [(i*16+bg)*64]
  int jmax[8];
  int wpar[8];
  int sigb[8];             // producer signal batch (slots)
};

__device__ __forceinline__ unsigned short f32_to_bf16(float f) {
  unsigned int u = __builtin_bit_cast(unsigned int, f);
  u = (u + 0x7FFFu + ((u >> 16) & 1u)) >> 16;  // RTNE (setup path only)
  return (unsigned short)u;
}
__device__ __forceinline__ float bf16_to_f32(unsigned short s) {
  unsigned int u = ((unsigned int)s) << 16;
  return __builtin_bit_cast(float, u);
}
// LDS-only barrier: drain own ds ops, sync; global traffic stays in flight.
__device__ __forceinline__ void lds_barrier() {
  asm volatile("s_waitcnt lgkmcnt(0)" ::: "memory");
  __builtin_amdgcn_s_barrier();
  asm volatile("" ::: "memory");
}
__device__ __forceinline__ void load_wfrag(const float* __restrict__ p, bf16x8& hi, bf16x8& lo) {
#pragma unroll
  for (int i = 0; i < 8; ++i) {
    float v = p[i];
    unsigned short h = f32_to_bf16(v);
    float rem = v - bf16_to_f32(h);
    hi[i] = (short)h;
    lo[i] = (short)f32_to_bf16(rem);
  }
}

// Fused pipeline. Grid: 128 WGs x 256 threads. WG -> (layer, batch-group).
// Lane-convention triple verified R1-R6 (A row=l&15; B col=l&15;
// k = kb*32+(l>>4)*8+s; C: value r of lane l -> row (l>>4)*4+r, col l&15).
__global__ __launch_bounds__(256, 1) void drnn_fused(Params P) {
  extern __shared__ __align__(16) char smem[];
  unsigned short (*Hhi)[16][136] = (unsigned short(*)[16][136])smem;          // 8704B
  unsigned short (*Hlo)[16][136] = (unsigned short(*)[16][136])(smem + 8704); // 8704B
  float* xlds = (float*)(smem + 17408);  // L0 only: [16][XPITCH] f32 = 50432B

  const int layer  = blockIdx.x >> 4;
  const int bg     = blockIdx.x & 15;
  const bool isL0   = (layer == 0);
  const bool isLast = (layer == 7);
  const int jmax = P.jmax[layer];
  const int wpar = P.wpar[layer];
  const int SIGB = P.sigb[layer];
  const float* __restrict__ Wih = P.Wih[layer];
  const float* __restrict__ Whh = P.Whh[layer];
  const float* __restrict__ bih = P.bih[layer];
  const float* __restrict__ bhh = P.bhh[layer];
  const unsigned short* __restrict__ Yin_hi = isL0 ? nullptr : P.phi[layer - 1];
  const unsigned short* __restrict__ Yin_lo = isL0 ? nullptr : P.plo[layer - 1];
  unsigned short* __restrict__ Yout_hi = isLast ? nullptr : P.phi[layer];
  unsigned short* __restrict__ Yout_lo = isLast ? nullptr : P.plo[layer];
  int* fin  = isL0 ? nullptr : P.flags + 64 * ((layer - 1) * 16 + bg);
  int* fout = isLast ? nullptr : P.flags + 64 * (layer * 16 + bg);

  const int tid  = threadIdx.x;
  const int wave = tid >> 6;      // 0..3
  const int lane = tid & 63;
  const int lrow = lane & 15;     // A row / B col / C col (batch)
  const int lgrp = lane >> 4;     // k-slot group; C row group
  const int b0   = bg << 4;

  // consumer flag cache: acquire (buffer_inv) only when crossing a batch
  int seen = 0;
  auto wait_in = [&](int need) {
    if (seen >= need) return;
    while (__hip_atomic_load(fin, __ATOMIC_RELAXED, __HIP_MEMORY_SCOPE_AGENT) < need)
      __builtin_amdgcn_s_sleep(2);
    seen = __hip_atomic_load(fin, __ATOMIC_ACQUIRE, __HIP_MEMORY_SCOPE_AGENT);
  };

  // ---- persistent weight A-frags ----
  bf16x8 whhh[2][4], whhl[2][4], wihh[2][4], wihl[2][4];
#pragma unroll
  for (int tl = 0; tl < 2; ++tl) {
    const float* wp = Whh + (size_t)(wave * 32 + tl * 16 + lrow) * HID + lgrp * 8;
#pragma unroll
    for (int kb = 0; kb < 4; ++kb)
      load_wfrag(wp + kb * 32, whhh[tl][kb], whhl[tl][kb]);
  }
  if (!isL0) {
#pragma unroll
    for (int tl = 0; tl < 2; ++tl) {
      const float* wp = Wih + (size_t)(wave * 32 + tl * 16 + lrow) * HID + lgrp * 8;
#pragma unroll
      for (int kb = 0; kb < 4; ++kb)
        load_wfrag(wp + kb * 32, wihh[tl][kb], wihl[tl][kb]);
    }
  }
  f32x4 bias_[2], w0_[2];
#pragma unroll
  for (int tl = 0; tl < 2; ++tl)
#pragma unroll
    for (int r = 0; r < 4; ++r) {
      const int n = wave * 32 + tl * 16 + lgrp * 4 + r;
      bias_[tl][r] = bih[n] + bhh[n];
      w0_[tl][r]   = isL0 ? Wih[n] : 0.0f;
    }

  // L0: preload this WG's x slice into LDS (one-time; removes ALL global
  // loads from L0's main loop).
  if (isL0) {
    for (int r = 0; r < 16; ++r)
      for (int i = tid; i < TSTEPS / 4; i += 256)
        *(f32x4*)&xlds[r * XPITCH + i * 4] =
            *(const f32x4*)&P.x0[(size_t)(b0 + r) * TSTEPS + i * 4];
    __syncthreads();
  }

  // x double-buffer (running-pointer plane prefetch; L0 reads LDS slab)
  bf16x8 xhA[4], xlA[4], xhB[4], xlB[4];
  float xvA = 0.f, xvB = 0.f;
  const unsigned short* pin_h = nullptr;
  const unsigned short* pin_l = nullptr;
  if (isL0) {
    xvA = xlds[lrow * XPITCH + 0];
  } else {
    wait_in(1);
    const size_t lofs = ((size_t)b0 + lrow) * HID + lgrp * 8;
    pin_h = Yin_hi + lofs;
    pin_l = Yin_lo + lofs;
#pragma unroll
    for (int kb = 0; kb < 4; ++kb) {
      xhA[kb] = *(const bf16x8*)(pin_h + kb * 32);
      xlA[kb] = *(const bf16x8*)(pin_l + kb * 32);
    }
    pin_h += SLOT_ELEMS;  // -> slot 1
    pin_l += SLOT_ELEMS;
  }

  // running-pointer coalesced writeback (slot sequence 0,1,2,...)
  unsigned short* wb_h = nullptr;
  unsigned short* wb_l = nullptr;
  if (!isLast) {
    const int row = tid >> 4, cb = tid & 15;
    const size_t wofs = ((size_t)b0 + row) * HID + cb * 8;
    wb_h = Yout_hi + wofs;
    wb_l = Yout_lo + wofs;
  }
  const int wsrc = (tid >> 4) * 136 + (tid & 15) * 8;  // LDS src offset (shorts)
  auto writeback = [&](int rp) {
    *(bf16x8*)wb_h = *(const bf16x8*)((const unsigned short*)&Hhi[rp][0][0] + wsrc);
    *(bf16x8*)wb_l = *(const bf16x8*)((const unsigned short*)&Hlo[rp][0][0] + wsrc);
    wb_h += SLOT_ELEMS;
    wb_l += SLOT_ELEMS;
  };

  int next_sig = SIGB;  // first in-loop signal when about to write slot SIGB

  auto step = [&](int j, bf16x8 (&xh_c)[4], bf16x8 (&xl_c)[4],
                  bf16x8 (&xh_n)[4], bf16x8 (&xl_n)[4],
                  float& xv_c, float& xv_n) {
    // prefetch input for step j+1 (gated by producer flag for slot j+1)
    if (j + 1 < jmax) {
      if (isL0) {
        xv_n = xlds[lrow * XPITCH + (j + 1)];
      } else {
        wait_in(j + 2);
#pragma unroll
        for (int kb = 0; kb < 4; ++kb) {
          xh_n[kb] = *(const bf16x8*)(pin_h + kb * 32);
          xl_n[kb] = *(const bf16x8*)(pin_l + kb * 32);
        }
        pin_h += SLOT_ELEMS;
        pin_l += SLOT_ELEMS;
      }
    }
    f32x4 c0[2], c1[2], c2[2];
#pragma unroll
    for (int tl = 0; tl < 2; ++tl) {
      c0[tl] = bias_[tl];
      c1[tl] = f32x4{0.f, 0.f, 0.f, 0.f};
      c2[tl] = f32x4{0.f, 0.f, 0.f, 0.f};
    }
    if (!isL0) {  // xW before the barrier (independent of h)
#pragma unroll
      for (int kb = 0; kb < 4; ++kb)
#pragma unroll
        for (int tl = 0; tl < 2; ++tl) {
          c0[tl] = __builtin_amdgcn_mfma_f32_16x16x32_bf16(wihh[tl][kb], xh_c[kb], c0[tl], 0, 0, 0);
          c1[tl] = __builtin_amdgcn_mfma_f32_16x16x32_bf16(wihl[tl][kb], xh_c[kb], c1[tl], 0, 0, 0);
          c2[tl] = __builtin_amdgcn_mfma_f32_16x16x32_bf16(wihh[tl][kb], xl_c[kb], c2[tl], 0, 0, 0);
        }
    }
    if (j > 0) {
      lds_barrier();  // H[rp] visible; global traffic stays in flight
      const int rp = (j - 1) & 1;
      bf16x8 bh[4], bl[4];
#pragma unroll
      for (int kb = 0; kb < 4; ++kb) {
        bh[kb] = *(const bf16x8*)&Hhi[rp][lrow][kb * 32 + lgrp * 8];
        bl[kb] = *(const bf16x8*)&Hlo[rp][lrow][kb * 32 + lgrp * 8];
      }
      if (!isLast && ((j - 1) & 1) == wpar) {
        const int wbslot = (j - 1 - wpar) >> 1;
        if (wbslot == next_sig) {
          // delayed batch signal: covers slots [0, wbslot) — their stores
          // were issued >=2 steps ago, so this vmcnt(0) is nearly free.
          asm volatile("s_waitcnt vmcnt(0)" ::: "memory");
          __builtin_amdgcn_s_barrier();
          if (tid == 0)
            __hip_atomic_store(fout, wbslot, __ATOMIC_RELEASE, __HIP_MEMORY_SCOPE_AGENT);
          next_sig += SIGB;
        }
        writeback(rp);
      }
#pragma unroll
      for (int kb = 0; kb < 4; ++kb)
#pragma unroll
        for (int tl = 0; tl < 2; ++tl) {
          c0[tl] = __builtin_amdgcn_mfma_f32_16x16x32_bf16(whhh[tl][kb], bh[kb], c0[tl], 0, 0, 0);
          c1[tl] = __builtin_amdgcn_mfma_f32_16x16x32_bf16(whhl[tl][kb], bh[kb], c1[tl], 0, 0, 0);
          c2[tl] = __builtin_amdgcn_mfma_f32_16x16x32_bf16(whhh[tl][kb], bl[kb], c2[tl], 0, 0, 0);
        }
    }
    const int pp = j & 1;
#pragma unroll
    for (int tl = 0; tl < 2; ++tl) {
      float y[4];
      f32x4 yv;
#pragma unroll
      for (int r = 0; r < 4; ++r) {
        float v = c0[tl][r] + c1[tl][r] + c2[tl][r];
        if (isL0) v = __builtin_fmaf(xv_c, w0_[tl][r], v);
        // tanh(v) = 1 - 2/(exp2(v*2log2e)+1)
        float t  = __builtin_amdgcn_exp2f(v * 2.885390081777927f);
        float rc = __builtin_amdgcn_rcpf(t + 1.0f);
        y[r] = __builtin_fmaf(-2.0f, rc, 1.0f);
        yv[r] = y[r];
      }
      // truncation hi/lo split (exact rem), packed with v_perm_b32
      float rem[4];
#pragma unroll
      for (int r = 0; r < 4; ++r) {
        float hf = __builtin_bit_cast(float,
            __builtin_bit_cast(unsigned int, y[r]) & 0xffff0000u);
        rem[r] = y[r] - hf;
      }
      u32x2 ph, pl;
      ph[0] = __builtin_amdgcn_perm(__builtin_bit_cast(unsigned int, y[1]),
                                    __builtin_bit_cast(unsigned int, y[0]), 0x07060302u);
      ph[1] = __builtin_amdgcn_perm(__builtin_bit_cast(unsigned int, y[3]),
                                    __builtin_bit_cast(unsigned int, y[2]), 0x07060302u);
      pl[0] = __builtin_amdgcn_perm(__builtin_bit_cast(unsigned int, rem[1]),
                                    __builtin_bit_cast(unsigned int, rem[0]), 0x07060302u);
      pl[1] = __builtin_amdgcn_perm(__builtin_bit_cast(unsigned int, rem[3]),
                                    __builtin_bit_cast(unsigned int, rem[2]), 0x07060302u);
      const int nb = wave * 32 + tl * 16 + lgrp * 4;
      *(u32x2*)&Hhi[pp][lrow][nb] = ph;
      *(u32x2*)&Hlo[pp][lrow][nb] = pl;
      if (isLast && j == jmax - 1)
        *(f32x4*)&P.hlast[(size_t)(b0 + lrow) * HID + nb] = yv;
    }
  };

  int j = 0;
  for (;;) {
    step(j, xhA, xlA, xhB, xlB, xvA, xvB);
    if (++j >= jmax) break;
    step(j, xhB, xlB, xhA, xlA, xvB, xvA);
    if (++j >= jmax) break;
  }

  if (!isLast) {
    if (((jmax - 1) & 1) == wpar) {  // last step's state, if consumed
      lds_barrier();
      writeback((jmax - 1) & 1);
    }
    // final signal: all slots ready (full drain)
    asm volatile("s_waitcnt vmcnt(0)" ::: "memory");
    __builtin_amdgcn_s_barrier();
    if (tid == 0)
      __hip_atomic_store(fout, ((jmax - 1 - wpar) >> 1) + 1,
                         __ATOMIC_RELEASE, __HIP_MEMORY_SCOPE_AGENT);
  }
}

// logits[b][n] = sum_k hlast[b][k] * W[k][n] + b[n]
__global__ __launch_bounds__(256) void logits_kernel(
    const float* __restrict__ hlast, const float* __restrict__ W,
    const float* __restrict__ bvec, float* __restrict__ out)
{
  __shared__ float Ws[HID * 10];
  const int tid = threadIdx.x;
  for (int i = tid; i < HID * 10; i += 256) Ws[i] = W[i];
  __syncthreads();
  float acc[10];
#pragma unroll
  for (int n = 0; n < 10; ++n) acc[n] = bvec[n];
  const float* h = hlast + (size_t)tid * HID;
#pragma unroll 4
  for (int k = 0; k < HID; ++k) {
    const float hv = h[k];
#pragma unroll
    for (int n = 0; n < 10; ++n) acc[n] += hv * Ws[k * 10 + n];
  }
#pragma unroll
  for (int n = 0; n < 10; ++n) out[(size_t)tid * 10 + n] = acc[n];
}

extern "C" void kernel_launch(void* const* d_in, const int* in_sizes, int n_in,
                              void* d_out, int out_size, void* d_ws, size_t ws_size,
                              hipStream_t stream) {
  (void)in_sizes; (void)n_in; (void)out_size; (void)ws_size;
  const float* x    = (const float*)d_in[0];   // (256,784,1)
  const float* Wih0 = (const float*)d_in[1];   // (128,1)
  const float* Whh0 = (const float*)d_in[2];   // (128,128)
  const float* bih0 = (const float*)d_in[3];
  const float* bhh0 = (const float*)d_in[4];
  const float* WihA = (const float*)d_in[5];   // (7,128,128)
  const float* WhhA = (const float*)d_in[6];   // (7,128,128)
  const float* bihA = (const float*)d_in[7];   // (7,128)
  const float* bhhA = (const float*)d_in[8];   // (7,128)
  const float* Wout = (const float*)d_in[9];   // (128,10)
  const float* bout = (const float*)d_in[10];  // (10,)
  float* out = (float*)d_out;

  // Pruned chains (R4 dataflow): chain c = 0,1,3,7,15,15,15,15
  static const int jmaxs[8] = {784, 392, 196, 98, 49, 25, 13, 7};
  static const int wpars[8] = {1, 1, 1, 1, 0, 0, 0, 0};
  static const int sigbs[8] = {8, 8, 8, 8, 4, 2, 2, 0};

  Params P;
  P.x0 = x;
  P.Wih[0] = Wih0; P.Whh[0] = Whh0; P.bih[0] = bih0; P.bhh[0] = bhh0;
  for (int i = 0; i < 7; ++i) {
    P.Wih[i + 1] = WihA + (size_t)i * HID * HID;
    P.Whh[i + 1] = WhhA + (size_t)i * HID * HID;
    P.bih[i + 1] = bihA + (size_t)i * HID;
    P.bhh[i + 1] = bhhA + (size_t)i * HID;
  }
  for (int i = 0; i < 8; ++i) {
    P.jmax[i] = jmaxs[i]; P.wpar[i] = wpars[i]; P.sigb[i] = sigbs[i];
  }

  // workspace: per-layer slot-compacted hi/lo planes (~102 MB) + hlast + flags
  unsigned short* wsp = (unsigned short*)d_ws;
  size_t off = 0;
  for (int i = 0; i < 7; ++i) {
    const size_t slots = (size_t)jmaxs[i + 1] * NBATCH * HID;
    P.phi[i] = wsp + off; off += slots;
    P.plo[i] = wsp + off; off += slots;
  }
  P.phi[7] = nullptr; P.plo[7] = nullptr;
  P.hlast = (float*)(wsp + off); off += (size_t)NBATCH * HID * 2;  // f32 = 2 shorts
  int* flags = (int*)(wsp + off);
  P.flags = flags;

  // allow >64KB dynamic LDS (84KB forces CU-exclusive workgroups)
  hipFuncSetAttribute((const void*)drnn_fused,
                      hipFuncAttributeMaxDynamicSharedMemorySize, DYN_LDS);

  hipMemsetAsync(flags, 0, 7 * 16 * 64 * sizeof(int), stream);
  drnn_fused<<<dim3(128), dim3(256), DYN_LDS, stream>>>(P);
  logits_kernel<<<dim3(1), dim3(256), 0, stream>>>(P.hlast, Wout, bout, out);
}

// Round 8
// 961.472 us; speedup vs baseline: 2.9263x; 1.0097x over previous
//
#include <hip/hip_runtime.h>

// Dilated RNN forward, MI355X. Round 8: fused pipeline, L3-coherent handshake.
//  - R7 structure: 128 WGs = 8 pruned layers x 16 batch-groups, pipelined,
//    84KB dynamic LDS (CU-exclusive), L0 x-slab in LDS, running pointers.
//  - NEW: NO cache-maintenance protocol. Plane writebacks are SYSTEM-scope
//    relaxed 8B stores (sc0 sc1 -> write-through to Infinity Cache, which is
//    memory-side and cross-XCD coherent). Flags are SYSTEM-scope relaxed
//    stores/loads (bypass L1/L2, hit L3). No buffer_wbl2 on signal, no
//    buffer_inv on wait -> removes ~7us/signal from the serial chain.
//    Ordering: per-wave vmcnt(0) before barrier+flag (data acked at L3
//    before flag issues); consumer loads issue in-order after poll retires;
//    every plane line is read once per XCD, always after its flag.

typedef __attribute__((ext_vector_type(8))) short bf16x8;
typedef __attribute__((ext_vector_type(4))) float f32x4;
typedef __attribute__((ext_vector_type(2))) unsigned int u32x2;
typedef __attribute__((ext_vector_type(2))) unsigned long long u64x2;

#define TSTEPS 784
#define NBATCH 256
#define HID 128
#define SLOT_ELEMS (NBATCH * HID)     // shorts per plane slot (32768)
#define XPITCH 788                    // f32 pitch for L0 x slab (2-way banks)
#define DYN_LDS 86016                 // 84KB -> 1 WG/CU; also fits x-slab

struct Params {
  const float* x0;
  const float* Wih[8];
  const float* Whh[8];
  const float* bih[8];
  const float* bhh[8];
  unsigned short* phi[8];  // slot-indexed output plane of layer i (i<7)
  unsigned short* plo[8];
  float* hlast;
  int* flags;              // flag (layer i -> i+1, bg) at [(i*16+bg)*64]
  int jmax[8];
  int wpar[8];
  int sigb[8];             // producer signal batch (slots)
};

__device__ __forceinline__ unsigned short f32_to_bf16(float f) {
  unsigned int u = __builtin_bit_cast(unsigned int, f);
  u = (u + 0x7FFFu + ((u >> 16) & 1u)) >> 16;  // RTNE (setup path only)
  return (unsigned short)u;
}
__device__ __forceinline__ float bf16_to_f32(unsigned short s) {
  unsigned int u = ((unsigned int)s) << 16;
  return __builtin_bit_cast(float, u);
}
// LDS-only barrier: drain own ds ops, sync; global traffic stays in flight.
__device__ __forceinline__ void lds_barrier() {
  asm volatile("s_waitcnt lgkmcnt(0)" ::: "memory");
  __builtin_amdgcn_s_barrier();
  asm volatile("" ::: "memory");
}
__device__ __forceinline__ void load_wfrag(const float* __restrict__ p, bf16x8& hi, bf16x8& lo) {
#pragma unroll
  for (int i = 0; i < 8; ++i) {
    float v = p[i];
    unsigned short h = f32_to_bf16(v);
    float rem = v - bf16_to_f32(h);
    hi[i] = (short)h;
    lo[i] = (short)f32_to_bf16(rem);
  }
}

// Fused pipeline. Grid: 128 WGs x 256 threads. WG -> (layer, batch-group).
// Lane-convention triple verified R1-R7 (A row=l&15; B col=l&15;
// k = kb*32+(l>>4)*8+s; C: value r of lane l -> row (l>>4)*4+r, col l&15).
__global__ __launch_bounds__(256, 1) void drnn_fused(Params P) {
  extern __shared__ __align__(16) char smem[];
  unsigned short (*Hhi)[16][136] = (unsigned short(*)[16][136])smem;          // 8704B
  unsigned short (*Hlo)[16][136] = (unsigned short(*)[16][136])(smem + 8704); // 8704B
  float* xlds = (float*)(smem + 17408);  // L0 only: [16][XPITCH] f32 = 50432B

  const int layer  = blockIdx.x >> 4;
  const int bg     = blockIdx.x & 15;
  const bool isL0   = (layer == 0);
  const bool isLast = (layer == 7);
  const int jmax = P.jmax[layer];
  const int wpar = P.wpar[layer];
  const int SIGB = P.sigb[layer];
  const float* __restrict__ Wih = P.Wih[layer];
  const float* __restrict__ Whh = P.Whh[layer];
  const float* __restrict__ bih = P.bih[layer];
  const float* __restrict__ bhh = P.bhh[layer];
  const unsigned short* __restrict__ Yin_hi = isL0 ? nullptr : P.phi[layer - 1];
  const unsigned short* __restrict__ Yin_lo = isL0 ? nullptr : P.plo[layer - 1];
  unsigned short* __restrict__ Yout_hi = isLast ? nullptr : P.phi[layer];
  unsigned short* __restrict__ Yout_lo = isLast ? nullptr : P.plo[layer];
  int* fin  = isL0 ? nullptr : P.flags + 64 * ((layer - 1) * 16 + bg);
  int* fout = isLast ? nullptr : P.flags + 64 * (layer * 16 + bg);

  const int tid  = threadIdx.x;
  const int wave = tid >> 6;      // 0..3
  const int lane = tid & 63;
  const int lrow = lane & 15;     // A row / B col / C col (batch)
  const int lgrp = lane >> 4;     // k-slot group; C row group
  const int b0   = bg << 4;

  // consumer flag cache: SYSTEM relaxed poll (L3 read, no cache maintenance)
  int seen = 0;
  auto wait_in = [&](int need) {
    if (seen >= need) return;
    while ((seen = __hip_atomic_load(fin, __ATOMIC_RELAXED,
                                     __HIP_MEMORY_SCOPE_SYSTEM)) < need)
      __builtin_amdgcn_s_sleep(2);
  };

  // ---- persistent weight A-frags ----
  bf16x8 whhh[2][4], whhl[2][4], wihh[2][4], wihl[2][4];
#pragma unroll
  for (int tl = 0; tl < 2; ++tl) {
    const float* wp = Whh + (size_t)(wave * 32 + tl * 16 + lrow) * HID + lgrp * 8;
#pragma unroll
    for (int kb = 0; kb < 4; ++kb)
      load_wfrag(wp + kb * 32, whhh[tl][kb], whhl[tl][kb]);
  }
  if (!isL0) {
#pragma unroll
    for (int tl = 0; tl < 2; ++tl) {
      const float* wp = Wih + (size_t)(wave * 32 + tl * 16 + lrow) * HID + lgrp * 8;
#pragma unroll
      for (int kb = 0; kb < 4; ++kb)
        load_wfrag(wp + kb * 32, wihh[tl][kb], wihl[tl][kb]);
    }
  }
  f32x4 bias_[2], w0_[2];
#pragma unroll
  for (int tl = 0; tl < 2; ++tl)
#pragma unroll
    for (int r = 0; r < 4; ++r) {
      const int n = wave * 32 + tl * 16 + lgrp * 4 + r;
      bias_[tl][r] = bih[n] + bhh[n];
      w0_[tl][r]   = isL0 ? Wih[n] : 0.0f;
    }

  // L0: preload this WG's x slice into LDS (removes all L0 global loads)
  if (isL0) {
    for (int r = 0; r < 16; ++r)
      for (int i = tid; i < TSTEPS / 4; i += 256)
        *(f32x4*)&xlds[r * XPITCH + i * 4] =
            *(const f32x4*)&P.x0[(size_t)(b0 + r) * TSTEPS + i * 4];
    __syncthreads();
  }

  // x double-buffer (running-pointer plane prefetch; L0 reads LDS slab)
  bf16x8 xhA[4], xlA[4], xhB[4], xlB[4];
  float xvA = 0.f, xvB = 0.f;
  const unsigned short* pin_h = nullptr;
  const unsigned short* pin_l = nullptr;
  if (isL0) {
    xvA = xlds[lrow * XPITCH + 0];
  } else {
    wait_in(1);
    const size_t lofs = ((size_t)b0 + lrow) * HID + lgrp * 8;
    pin_h = Yin_hi + lofs;
    pin_l = Yin_lo + lofs;
#pragma unroll
    for (int kb = 0; kb < 4; ++kb) {
      xhA[kb] = *(const bf16x8*)(pin_h + kb * 32);
      xlA[kb] = *(const bf16x8*)(pin_l + kb * 32);
    }
    pin_h += SLOT_ELEMS;  // -> slot 1
    pin_l += SLOT_ELEMS;
  }

  // running-pointer coalesced writeback; SYSTEM-scope 8B stores (sc0 sc1:
  // write-through to L3 -> cross-XCD visible without any wbl2)
  unsigned long long* wb_h = nullptr;
  unsigned long long* wb_l = nullptr;
  if (!isLast) {
    const int row = tid >> 4, cb = tid & 15;
    const size_t wofs = ((size_t)b0 + row) * HID + cb * 8;
    wb_h = (unsigned long long*)(Yout_hi + wofs);
    wb_l = (unsigned long long*)(Yout_lo + wofs);
  }
  const int wsrc = (tid >> 4) * 136 + (tid & 15) * 8;  // LDS src offset (shorts)
  auto writeback = [&](int rp) {
    u64x2 vh = *(const u64x2*)((const unsigned short*)&Hhi[rp][0][0] + wsrc);
    u64x2 vl = *(const u64x2*)((const unsigned short*)&Hlo[rp][0][0] + wsrc);
    __hip_atomic_store(wb_h,     vh[0], __ATOMIC_RELAXED, __HIP_MEMORY_SCOPE_SYSTEM);
    __hip_atomic_store(wb_h + 1, vh[1], __ATOMIC_RELAXED, __HIP_MEMORY_SCOPE_SYSTEM);
    __hip_atomic_store(wb_l,     vl[0], __ATOMIC_RELAXED, __HIP_MEMORY_SCOPE_SYSTEM);
    __hip_atomic_store(wb_l + 1, vl[1], __ATOMIC_RELAXED, __HIP_MEMORY_SCOPE_SYSTEM);
    wb_h += SLOT_ELEMS / 4;   // shorts -> u64 units
    wb_l += SLOT_ELEMS / 4;
  };
  // signal: per-wave drain of (old, long-acked) stores; barrier; bare flag
  // store to L3. No cache maintenance anywhere.
  auto signal = [&](int val) {
    asm volatile("s_waitcnt vmcnt(0)" ::: "memory");
    __builtin_amdgcn_s_barrier();
    if (tid == 0)
      __hip_atomic_store(fout, val, __ATOMIC_RELAXED, __HIP_MEMORY_SCOPE_SYSTEM);
  };

  int next_sig = SIGB;  // first in-loop signal when about to write slot SIGB

  auto step = [&](int j, bf16x8 (&xh_c)[4], bf16x8 (&xl_c)[4],
                  bf16x8 (&xh_n)[4], bf16x8 (&xl_n)[4],
                  float& xv_c, float& xv_n) {
    // prefetch input for step j+1 (gated by producer flag for slot j+1)
    if (j + 1 < jmax) {
      if (isL0) {
        xv_n = xlds[lrow * XPITCH + (j + 1)];
      } else {
        wait_in(j + 2);
#pragma unroll
        for (int kb = 0; kb < 4; ++kb) {
          xh_n[kb] = *(const bf16x8*)(pin_h + kb * 32);
          xl_n[kb] = *(const bf16x8*)(pin_l + kb * 32);
        }
        pin_h += SLOT_ELEMS;
        pin_l += SLOT_ELEMS;
      }
    }
    f32x4 c0[2], c1[2], c2[2];
#pragma unroll
    for (int tl = 0; tl < 2; ++tl) {
      c0[tl] = bias_[tl];
      c1[tl] = f32x4{0.f, 0.f, 0.f, 0.f};
      c2[tl] = f32x4{0.f, 0.f, 0.f, 0.f};
    }
    if (!isL0) {  // xW before the barrier (independent of h)
#pragma unroll
      for (int kb = 0; kb < 4; ++kb)
#pragma unroll
        for (int tl = 0; tl < 2; ++tl) {
          c0[tl] = __builtin_amdgcn_mfma_f32_16x16x32_bf16(wihh[tl][kb], xh_c[kb], c0[tl], 0, 0, 0);
          c1[tl] = __builtin_amdgcn_mfma_f32_16x16x32_bf16(wihl[tl][kb], xh_c[kb], c1[tl], 0, 0, 0);
          c2[tl] = __builtin_amdgcn_mfma_f32_16x16x32_bf16(wihh[tl][kb], xl_c[kb], c2[tl], 0, 0, 0);
        }
    }
    if (j > 0) {
      lds_barrier();  // H[rp] visible; global traffic stays in flight
      const int rp = (j - 1) & 1;
      bf16x8 bh[4], bl[4];
#pragma unroll
      for (int kb = 0; kb < 4; ++kb) {
        bh[kb] = *(const bf16x8*)&Hhi[rp][lrow][kb * 32 + lgrp * 8];
        bl[kb] = *(const bf16x8*)&Hlo[rp][lrow][kb * 32 + lgrp * 8];
      }
      if (!isLast && ((j - 1) & 1) == wpar) {
        const int wbslot = (j - 1 - wpar) >> 1;
        if (wbslot == next_sig) {
          signal(wbslot);   // covers slots [0, wbslot), stores long acked
          next_sig += SIGB;
        }
        writeback(rp);
      }
#pragma unroll
      for (int kb = 0; kb < 4; ++kb)
#pragma unroll
        for (int tl = 0; tl < 2; ++tl) {
          c0[tl] = __builtin_amdgcn_mfma_f32_16x16x32_bf16(whhh[tl][kb], bh[kb], c0[tl], 0, 0, 0);
          c1[tl] = __builtin_amdgcn_mfma_f32_16x16x32_bf16(whhl[tl][kb], bh[kb], c1[tl], 0, 0, 0);
          c2[tl] = __builtin_amdgcn_mfma_f32_16x16x32_bf16(whhh[tl][kb], bl[kb], c2[tl], 0, 0, 0);
        }
    }
    const int pp = j & 1;
#pragma unroll
    for (int tl = 0; tl < 2; ++tl) {
      float y[4];
      f32x4 yv;
#pragma unroll
      for (int r = 0; r < 4; ++r) {
        float v = c0[tl][r] + c1[tl][r] + c2[tl][r];
        if (isL0) v = __builtin_fmaf(xv_c, w0_[tl][r], v);
        // tanh(v) = 1 - 2/(exp2(v*2log2e)+1)
        float t  = __builtin_amdgcn_exp2f(v * 2.885390081777927f);
        float rc = __builtin_amdgcn_rcpf(t + 1.0f);
        y[r] = __builtin_fmaf(-2.0f, rc, 1.0f);
        yv[r] = y[r];
      }
      // truncation hi/lo split (exact rem), packed with v_perm_b32
      float rem[4];
#pragma unroll
      for (int r = 0; r < 4; ++r) {
        float hf = __builtin_bit_cast(float,
            __builtin_bit_cast(unsigned int, y[r]) & 0xffff0000u);
        rem[r] = y[r] - hf;
      }
      u32x2 ph, pl;
      ph[0] = __builtin_amdgcn_perm(__builtin_bit_cast(unsigned int, y[1]),
                                    __builtin_bit_cast(unsigned int, y[0]), 0x07060302u);
      ph[1] = __builtin_amdgcn_perm(__builtin_bit_cast(unsigned int, y[3]),
                                    __builtin_bit_cast(unsigned int, y[2]), 0x07060302u);
      pl[0] = __builtin_amdgcn_perm(__builtin_bit_cast(unsigned int, rem[1]),
                                    __builtin_bit_cast(unsigned int, rem[0]), 0x07060302u);
      pl[1] = __builtin_amdgcn_perm(__builtin_bit_cast(unsigned int, rem[3]),
                                    __builtin_bit_cast(unsigned int, rem[2]), 0x07060302u);
      const int nb = wave * 32 + tl * 16 + lgrp * 4;
      *(u32x2*)&Hhi[pp][lrow][nb] = ph;
      *(u32x2*)&Hlo[pp][lrow][nb] = pl;
      if (isLast && j == jmax - 1)
        *(f32x4*)&P.hlast[(size_t)(b0 + lrow) * HID + nb] = yv;
    }
  };

  int j = 0;
  for (;;) {
    step(j, xhA, xlA, xhB, xlB, xvA, xvB);
    if (++j >= jmax) break;
    step(j, xhB, xlB, xhA, xlA, xvB, xvA);
    if (++j >= jmax) break;
  }

  if (!isLast) {
    if (((jmax - 1) & 1) == wpar) {  // last step's state, if consumed
      lds_barrier();
      writeback((jmax - 1) & 1);
    }
    signal(((jmax - 1 - wpar) >> 1) + 1);  // all slots ready
  }
}

// logits[b][n] = sum_k hlast[b][k] * W[k][n] + b[n]
__global__ __launch_bounds__(256) void logits_kernel(
    const float* __restrict__ hlast, const float* __restrict__ W,
    const float* __restrict__ bvec, float* __restrict__ out)
{
  __shared__ float Ws[HID * 10];
  const int tid = threadIdx.x;
  for (int i = tid; i < HID * 10; i += 256) Ws[i] = W[i];
  __syncthreads();
  float acc[10];
#pragma unroll
  for (int n = 0; n < 10; ++n) acc[n] = bvec[n];
  const float* h = hlast + (size_t)tid * HID;
#pragma unroll 4
  for (int k = 0; k < HID; ++k) {
    const float hv = h[k];
#pragma unroll
    for (int n = 0; n < 10; ++n) acc[n] += hv * Ws[k * 10 + n];
  }
#pragma unroll
  for (int n = 0; n < 10; ++n) out[(size_t)tid * 10 + n] = acc[n];
}

extern "C" void kernel_launch(void* const* d_in, const int* in_sizes, int n_in,
                              void* d_out, int out_size, void* d_ws, size_t ws_size,
                              hipStream_t stream) {
  (void)in_sizes; (void)n_in; (void)out_size; (void)ws_size;
  const float* x    = (const float*)d_in[0];   // (256,784,1)
  const float* Wih0 = (const float*)d_in[1];   // (128,1)
  const float* Whh0 = (const float*)d_in[2];   // (128,128)
  const float* bih0 = (const float*)d_in[3];
  const float* bhh0 = (const float*)d_in[4];
  const float* WihA = (const float*)d_in[5];   // (7,128,128)
  const float* WhhA = (const float*)d_in[6];   // (7,128,128)
  const float* bihA = (const float*)d_in[7];   // (7,128)
  const float* bhhA = (const float*)d_in[8];   // (7,128)
  const float* Wout = (const float*)d_in[9];   // (128,10)
  const float* bout = (const float*)d_in[10];  // (10,)
  float* out = (float*)d_out;

  // Pruned chains (R4 dataflow): chain c = 0,1,3,7,15,15,15,15
  static const int jmaxs[8] = {784, 392, 196, 98, 49, 25, 13, 7};
  static const int wpars[8] = {1, 1, 1, 1, 0, 0, 0, 0};
  static const int sigbs[8] = {8, 8, 8, 8, 4, 2, 2, 0};

  Params P;
  P.x0 = x;
  P.Wih[0] = Wih0; P.Whh[0] = Whh0; P.bih[0] = bih0; P.bhh[0] = bhh0;
  for (int i = 0; i < 7; ++i) {
    P.Wih[i + 1] = WihA + (size_t)i * HID * HID;
    P.Whh[i + 1] = WhhA + (size_t)i * HID * HID;
    P.bih[i + 1] = bihA + (size_t)i * HID;
    P.bhh[i + 1] = bhhA + (size_t)i * HID;
  }
  for (int i = 0; i < 8; ++i) {
    P.jmax[i] = jmaxs[i]; P.wpar[i] = wpars[i]; P.sigb[i] = sigbs[i];
  }

  // workspace: per-layer slot-compacted hi/lo planes (~102 MB) + hlast + flags
  unsigned short* wsp = (unsigned short*)d_ws;
  size_t off = 0;
  for (int i = 0; i < 7; ++i) {
    const size_t slots = (size_t)jmaxs[i + 1] * NBATCH * HID;
    P.phi[i] = wsp + off; off += slots;
    P.plo[i] = wsp + off; off += slots;
  }
  P.phi[7] = nullptr; P.plo[7] = nullptr;
  P.hlast = (float*)(wsp + off); off += (size_t)NBATCH * HID * 2;  // f32 = 2 shorts
  int* flags = (int*)(wsp + off);
  P.flags = flags;

  // allow >64KB dynamic LDS (84KB: CU-exclusive + L0 x-slab)
  hipFuncSetAttribute((const void*)drnn_fused,
                      hipFuncAttributeMaxDynamicSharedMemorySize, DYN_LDS);

  hipMemsetAsync(flags, 0, 7 * 16 * 64 * sizeof(int), stream);
  drnn_fused<<<dim3(128), dim3(256), DYN_LDS, stream>>>(P);
  logits_kernel<<<dim3(1), dim3(256), 0, stream>>>(P.hlast, Wout, bout, out);
}

// Round 10
// 960.273 us; speedup vs baseline: 2.9300x; 1.0012x over previous
//
#include <hip/hip_runtime.h>

// Dilated RNN forward, MI355X. Round 9 (resubmit — R9 bench never acquired a
// GPU): Taylor-merge split epilogue.
//  - R8 structure: 128 WGs = 8 pruned layers x 16 batch-groups, pipelined via
//    batched delayed L3-coherent flags; 84KB LDS (CU-exclusive); L0 x-slab in
//    LDS; SYSTEM-scope write-through plane stores.
//  - NEW: first-order Taylor epilogue. y0 = tanh(c0) starts right after the
//    short hi*hi MFMA chain (8 MFMAs); the 16 lo-split MFMAs (c1=W_lo*h_hi,
//    c2=W_hi*h_lo) run on the matrix pipe concurrently with the tanh
//    trans/VALU work; merge y = y0 + (1-y0^2)*(c1+c2). Error ~3e-6/step.
//    Rationale: single-wave MFMA issue is ~19.4cy/instr on its SIMD (m06
//    ceiling is per-1024-SIMDs), so the 24-MFMA chain was ~465cy serialized
//    BEFORE the epilogue could start; now only 8 MFMAs gate the trans ops.

typedef __attribute__((ext_vector_type(8))) short bf16x8;
typedef __attribute__((ext_vector_type(4))) float f32x4;
typedef __attribute__((ext_vector_type(2))) unsigned int u32x2;
typedef __attribute__((ext_vector_type(2))) unsigned long long u64x2;

#define TSTEPS 784
#define NBATCH 256
#define HID 128
#define SLOT_ELEMS (NBATCH * HID)     // shorts per plane slot (32768)
#define XPITCH 788                    // f32 pitch for L0 x slab (2-way banks)
#define DYN_LDS 86016                 // 84KB -> 1 WG/CU; also fits x-slab

struct Params {
  const float* x0;
  const float* Wih[8];
  const float* Whh[8];
  const float* bih[8];
  const float* bhh[8];
  unsigned short* phi[8];  // slot-indexed output plane of layer i (i<7)
  unsigned short* plo[8];
  float* hlast;
  int* flags;              // flag (layer i -> i+1, bg) at [(i*16+bg)*64]
  int jmax[8];
  int wpar[8];
  int sigb[8];             // producer signal batch (slots)
};

__device__ __forceinline__ unsigned short f32_to_bf16(float f) {
  unsigned int u = __builtin_bit_cast(unsigned int, f);
  u = (u + 0x7FFFu + ((u >> 16) & 1u)) >> 16;  // RTNE (setup path only)
  return (unsigned short)u;
}
__device__ __forceinline__ float bf16_to_f32(unsigned short s) {
  unsigned int u = ((unsigned int)s) << 16;
  return __builtin_bit_cast(float, u);
}
// LDS-only barrier: drain own ds ops, sync; global traffic stays in flight.
__device__ __forceinline__ void lds_barrier() {
  asm volatile("s_waitcnt lgkmcnt(0)" ::: "memory");
  __builtin_amdgcn_s_barrier();
  asm volatile("" ::: "memory");
}
__device__ __forceinline__ void load_wfrag(const float* __restrict__ p, bf16x8& hi, bf16x8& lo) {
#pragma unroll
  for (int i = 0; i < 8; ++i) {
    float v = p[i];
    unsigned short h = f32_to_bf16(v);
    float rem = v - bf16_to_f32(h);
    hi[i] = (short)h;
    lo[i] = (short)f32_to_bf16(rem);
  }
}

// Fused pipeline. Grid: 128 WGs x 256 threads. WG -> (layer, batch-group).
// Lane-convention triple verified R1-R8 (A row=l&15; B col=l&15;
// k = kb*32+(l>>4)*8+s; C: value r of lane l -> row (l>>4)*4+r, col l&15).
__global__ __launch_bounds__(256, 1) void drnn_fused(Params P) {
  extern __shared__ __align__(16) char smem[];
  unsigned short (*Hhi)[16][136] = (unsigned short(*)[16][136])smem;          // 8704B
  unsigned short (*Hlo)[16][136] = (unsigned short(*)[16][136])(smem + 8704); // 8704B
  float* xlds = (float*)(smem + 17408);  // L0 only: [16][XPITCH] f32 = 50432B

  const int layer  = blockIdx.x >> 4;
  const int bg     = blockIdx.x & 15;
  const bool isL0   = (layer == 0);
  const bool isLast = (layer == 7);
  const int jmax = P.jmax[layer];
  const int wpar = P.wpar[layer];
  const int SIGB = P.sigb[layer];
  const float* __restrict__ Wih = P.Wih[layer];
  const float* __restrict__ Whh = P.Whh[layer];
  const float* __restrict__ bih = P.bih[layer];
  const float* __restrict__ bhh = P.bhh[layer];
  const unsigned short* __restrict__ Yin_hi = isL0 ? nullptr : P.phi[layer - 1];
  const unsigned short* __restrict__ Yin_lo = isL0 ? nullptr : P.plo[layer - 1];
  unsigned short* __restrict__ Yout_hi = isLast ? nullptr : P.phi[layer];
  unsigned short* __restrict__ Yout_lo = isLast ? nullptr : P.plo[layer];
  int* fin  = isL0 ? nullptr : P.flags + 64 * ((layer - 1) * 16 + bg);
  int* fout = isLast ? nullptr : P.flags + 64 * (layer * 16 + bg);

  const int tid  = threadIdx.x;
  const int wave = tid >> 6;      // 0..3
  const int lane = tid & 63;
  const int lrow = lane & 15;     // A row / B col / C col (batch)
  const int lgrp = lane >> 4;     // k-slot group; C row group
  const int b0   = bg << 4;

  // consumer flag cache: SYSTEM relaxed poll (L3 read, no cache maintenance)
  int seen = 0;
  auto wait_in = [&](int need) {
    if (seen >= need) return;
    while ((seen = __hip_atomic_load(fin, __ATOMIC_RELAXED,
                                     __HIP_MEMORY_SCOPE_SYSTEM)) < need)
      __builtin_amdgcn_s_sleep(2);
  };

  // ---- persistent weight A-frags ----
  bf16x8 whhh[2][4], whhl[2][4], wihh[2][4], wihl[2][4];
#pragma unroll
  for (int tl = 0; tl < 2; ++tl) {
    const float* wp = Whh + (size_t)(wave * 32 + tl * 16 + lrow) * HID + lgrp * 8;
#pragma unroll
    for (int kb = 0; kb < 4; ++kb)
      load_wfrag(wp + kb * 32, whhh[tl][kb], whhl[tl][kb]);
  }
  if (!isL0) {
#pragma unroll
    for (int tl = 0; tl < 2; ++tl) {
      const float* wp = Wih + (size_t)(wave * 32 + tl * 16 + lrow) * HID + lgrp * 8;
#pragma unroll
      for (int kb = 0; kb < 4; ++kb)
        load_wfrag(wp + kb * 32, wihh[tl][kb], wihl[tl][kb]);
    }
  }
  f32x4 bias_[2], w0_[2];
#pragma unroll
  for (int tl = 0; tl < 2; ++tl)
#pragma unroll
    for (int r = 0; r < 4; ++r) {
      const int n = wave * 32 + tl * 16 + lgrp * 4 + r;
      bias_[tl][r] = bih[n] + bhh[n];
      w0_[tl][r]   = isL0 ? Wih[n] : 0.0f;
    }

  // L0: preload this WG's x slice into LDS (removes all L0 global loads)
  if (isL0) {
    for (int r = 0; r < 16; ++r)
      for (int i = tid; i < TSTEPS / 4; i += 256)
        *(f32x4*)&xlds[r * XPITCH + i * 4] =
            *(const f32x4*)&P.x0[(size_t)(b0 + r) * TSTEPS + i * 4];
    __syncthreads();
  }

  // x double-buffer (running-pointer plane prefetch; L0 reads LDS slab)
  bf16x8 xhA[4], xlA[4], xhB[4], xlB[4];
  float xvA = 0.f, xvB = 0.f;
  const unsigned short* pin_h = nullptr;
  const unsigned short* pin_l = nullptr;
  if (isL0) {
    xvA = xlds[lrow * XPITCH + 0];
  } else {
    wait_in(1);
    const size_t lofs = ((size_t)b0 + lrow) * HID + lgrp * 8;
    pin_h = Yin_hi + lofs;
    pin_l = Yin_lo + lofs;
#pragma unroll
    for (int kb = 0; kb < 4; ++kb) {
      xhA[kb] = *(const bf16x8*)(pin_h + kb * 32);
      xlA[kb] = *(const bf16x8*)(pin_l + kb * 32);
    }
    pin_h += SLOT_ELEMS;  // -> slot 1
    pin_l += SLOT_ELEMS;
  }

  // running-pointer coalesced writeback; SYSTEM-scope 8B stores (write-
  // through to L3 -> cross-XCD visible without any cache maintenance)
  unsigned long long* wb_h = nullptr;
  unsigned long long* wb_l = nullptr;
  if (!isLast) {
    const int row = tid >> 4, cb = tid & 15;
    const size_t wofs = ((size_t)b0 + row) * HID + cb * 8;
    wb_h = (unsigned long long*)(Yout_hi + wofs);
    wb_l = (unsigned long long*)(Yout_lo + wofs);
  }
  const int wsrc = (tid >> 4) * 136 + (tid & 15) * 8;  // LDS src offset (shorts)
  auto writeback = [&](int rp) {
    u64x2 vh = *(const u64x2*)((const unsigned short*)&Hhi[rp][0][0] + wsrc);
    u64x2 vl = *(const u64x2*)((const unsigned short*)&Hlo[rp][0][0] + wsrc);
    __hip_atomic_store(wb_h,     vh[0], __ATOMIC_RELAXED, __HIP_MEMORY_SCOPE_SYSTEM);
    __hip_atomic_store(wb_h + 1, vh[1], __ATOMIC_RELAXED, __HIP_MEMORY_SCOPE_SYSTEM);
    __hip_atomic_store(wb_l,     vl[0], __ATOMIC_RELAXED, __HIP_MEMORY_SCOPE_SYSTEM);
    __hip_atomic_store(wb_l + 1, vl[1], __ATOMIC_RELAXED, __HIP_MEMORY_SCOPE_SYSTEM);
    wb_h += SLOT_ELEMS / 4;   // shorts -> u64 units
    wb_l += SLOT_ELEMS / 4;
  };
  // signal: per-wave drain of (old, long-acked) stores; barrier; bare flag
  auto signal = [&](int val) {
    asm volatile("s_waitcnt vmcnt(0)" ::: "memory");
    __builtin_amdgcn_s_barrier();
    if (tid == 0)
      __hip_atomic_store(fout, val, __ATOMIC_RELAXED, __HIP_MEMORY_SCOPE_SYSTEM);
  };

  int next_sig = SIGB;  // first in-loop signal when about to write slot SIGB

  auto step = [&](int j, bf16x8 (&xh_c)[4], bf16x8 (&xl_c)[4],
                  bf16x8 (&xh_n)[4], bf16x8 (&xl_n)[4],
                  float& xv_c, float& xv_n) {
    // prefetch input for step j+1 (gated by producer flag for slot j+1)
    if (j + 1 < jmax) {
      if (isL0) {
        xv_n = xlds[lrow * XPITCH + (j + 1)];
      } else {
        wait_in(j + 2);
#pragma unroll
        for (int kb = 0; kb < 4; ++kb) {
          xh_n[kb] = *(const bf16x8*)(pin_h + kb * 32);
          xl_n[kb] = *(const bf16x8*)(pin_l + kb * 32);
        }
        pin_h += SLOT_ELEMS;
        pin_l += SLOT_ELEMS;
      }
    }
    // c0 = hi*hi (+bias); c1 = W_lo*in_hi; c2 = W_hi*in_lo
    f32x4 c0[2], c1[2], c2[2];
#pragma unroll
    for (int tl = 0; tl < 2; ++tl) {
      c0[tl] = bias_[tl];
      c1[tl] = f32x4{0.f, 0.f, 0.f, 0.f};
      c2[tl] = f32x4{0.f, 0.f, 0.f, 0.f};
    }
    if (!isL0) {  // xW before the barrier (independent of h)
#pragma unroll
      for (int kb = 0; kb < 4; ++kb)
#pragma unroll
        for (int tl = 0; tl < 2; ++tl) {
          c0[tl] = __builtin_amdgcn_mfma_f32_16x16x32_bf16(wihh[tl][kb], xh_c[kb], c0[tl], 0, 0, 0);
          c1[tl] = __builtin_amdgcn_mfma_f32_16x16x32_bf16(wihl[tl][kb], xh_c[kb], c1[tl], 0, 0, 0);
          c2[tl] = __builtin_amdgcn_mfma_f32_16x16x32_bf16(wihh[tl][kb], xl_c[kb], c2[tl], 0, 0, 0);
        }
    }
    bf16x8 bh[4], bl[4];
    if (j > 0) {
      lds_barrier();  // H[rp] visible; global traffic stays in flight
      const int rp = (j - 1) & 1;
#pragma unroll
      for (int kb = 0; kb < 4; ++kb)   // bh first: c0 starts on partial lgkm
        bh[kb] = *(const bf16x8*)&Hhi[rp][lrow][kb * 32 + lgrp * 8];
#pragma unroll
      for (int kb = 0; kb < 4; ++kb)
        bl[kb] = *(const bf16x8*)&Hlo[rp][lrow][kb * 32 + lgrp * 8];
      if (!isLast && ((j - 1) & 1) == wpar) {
        const int wbslot = (j - 1 - wpar) >> 1;
        if (wbslot == next_sig) {
          signal(wbslot);   // covers slots [0, wbslot), stores long acked
          next_sig += SIGB;
        }
        writeback(rp);
      }
      // Phase 1 (critical): hi*hi chain only — 8 MFMAs gate the tanh.
#pragma unroll
      for (int kb = 0; kb < 4; ++kb)
#pragma unroll
        for (int tl = 0; tl < 2; ++tl)
          c0[tl] = __builtin_amdgcn_mfma_f32_16x16x32_bf16(whhh[tl][kb], bh[kb], c0[tl], 0, 0, 0);
    }
    // Phase 2: y0 = tanh(c0) — trans/VALU pipe, overlaps Phase 3's MFMAs.
    float y0[2][4];
#pragma unroll
    for (int tl = 0; tl < 2; ++tl)
#pragma unroll
      for (int r = 0; r < 4; ++r) {
        float v = c0[tl][r];
        if (isL0) v = __builtin_fmaf(xv_c, w0_[tl][r], v);
        float t  = __builtin_amdgcn_exp2f(v * 2.885390081777927f);
        float rc = __builtin_amdgcn_rcpf(t + 1.0f);
        y0[tl][r] = __builtin_fmaf(-2.0f, rc, 1.0f);
      }
    // Phase 3: lo-split chains (matrix pipe; independent of Phase 2).
    if (j > 0) {
#pragma unroll
      for (int kb = 0; kb < 4; ++kb)
#pragma unroll
        for (int tl = 0; tl < 2; ++tl) {
          c1[tl] = __builtin_amdgcn_mfma_f32_16x16x32_bf16(whhl[tl][kb], bh[kb], c1[tl], 0, 0, 0);
          c2[tl] = __builtin_amdgcn_mfma_f32_16x16x32_bf16(whhh[tl][kb], bl[kb], c2[tl], 0, 0, 0);
        }
    }
    // Phase 4: Taylor merge y = y0 + (1-y0^2)*(c1+c2); split; pack; write.
    const int pp = j & 1;
#pragma unroll
    for (int tl = 0; tl < 2; ++tl) {
      float y[4];
      f32x4 yv;
#pragma unroll
      for (int r = 0; r < 4; ++r) {
        const float d = c1[tl][r] + c2[tl][r];
        const float s = __builtin_fmaf(-y0[tl][r], y0[tl][r], 1.0f);
        y[r] = __builtin_fmaf(s, d, y0[tl][r]);
        yv[r] = y[r];
      }
      float rem[4];
#pragma unroll
      for (int r = 0; r < 4; ++r) {
        float hf = __builtin_bit_cast(float,
            __builtin_bit_cast(unsigned int, y[r]) & 0xffff0000u);
        rem[r] = y[r] - hf;   // exact (Sterbenz); lo covers to 2^-16 rel
      }
      u32x2 ph, pl;
      ph[0] = __builtin_amdgcn_perm(__builtin_bit_cast(unsigned int, y[1]),
                                    __builtin_bit_cast(unsigned int, y[0]), 0x07060302u);
      ph[1] = __builtin_amdgcn_perm(__builtin_bit_cast(unsigned int, y[3]),
                                    __builtin_bit_cast(unsigned int, y[2]), 0x07060302u);
      pl[0] = __builtin_amdgcn_perm(__builtin_bit_cast(unsigned int, rem[1]),
                                    __builtin_bit_cast(unsigned int, rem[0]), 0x07060302u);
      pl[1] = __builtin_amdgcn_perm(__builtin_bit_cast(unsigned int, rem[3]),
                                    __builtin_bit_cast(unsigned int, rem[2]), 0x07060302u);
      const int nb = wave * 32 + tl * 16 + lgrp * 4;
      *(u32x2*)&Hhi[pp][lrow][nb] = ph;
      *(u32x2*)&Hlo[pp][lrow][nb] = pl;
      if (isLast && j == jmax - 1)
        *(f32x4*)&P.hlast[(size_t)(b0 + lrow) * HID + nb] = yv;
    }
  };

  int j = 0;
  for (;;) {
    step(j, xhA, xlA, xhB, xlB, xvA, xvB);
    if (++j >= jmax) break;
    step(j, xhB, xlB, xhA, xlA, xvB, xvA);
    if (++j >= jmax) break;
  }

  if (!isLast) {
    if (((jmax - 1) & 1) == wpar) {  // last step's state, if consumed
      lds_barrier();
      writeback((jmax - 1) & 1);
    }
    signal(((jmax - 1 - wpar) >> 1) + 1);  // all slots ready
  }
}

// logits[b][n] = sum_k hlast[b][k] * W[k][n] + b[n]
__global__ __launch_bounds__(256) void logits_kernel(
    const float* __restrict__ hlast, const float* __restrict__ W,
    const float* __restrict__ bvec, float* __restrict__ out)
{
  __shared__ float Ws[HID * 10];
  const int tid = threadIdx.x;
  for (int i = tid; i < HID * 10; i += 256) Ws[i] = W[i];
  __syncthreads();
  float acc[10];
#pragma unroll
  for (int n = 0; n < 10; ++n) acc[n] = bvec[n];
  const float* h = hlast + (size_t)tid * HID;
#pragma unroll 4
  for (int k = 0; k < HID; ++k) {
    const float hv = h[k];
#pragma unroll
    for (int n = 0; n < 10; ++n) acc[n] += hv * Ws[k * 10 + n];
  }
#pragma unroll
  for (int n = 0; n < 10; ++n) out[(size_t)tid * 10 + n] = acc[n];
}

extern "C" void kernel_launch(void* const* d_in, const int* in_sizes, int n_in,
                              void* d_out, int out_size, void* d_ws, size_t ws_size,
                              hipStream_t stream) {
  (void)in_sizes; (void)n_in; (void)out_size; (void)ws_size;
  const float* x    = (const float*)d_in[0];   // (256,784,1)
  const float* Wih0 = (const float*)d_in[1];   // (128,1)
  const float* Whh0 = (const float*)d_in[2];   // (128,128)
  const float* bih0 = (const float*)d_in[3];
  const float* bhh0 = (const float*)d_in[4];
  const float* WihA = (const float*)d_in[5];   // (7,128,128)
  const float* WhhA = (const float*)d_in[6];   // (7,128,128)
  const float* bihA = (const float*)d_in[7];   // (7,128)
  const float* bhhA = (const float*)d_in[8];   // (7,128)
  const float* Wout = (const float*)d_in[9];   // (128,10)
  const float* bout = (const float*)d_in[10];  // (10,)
  float* out = (float*)d_out;

  // Pruned chains (R4 dataflow): chain c = 0,1,3,7,15,15,15,15
  static const int jmaxs[8] = {784, 392, 196, 98, 49, 25, 13, 7};
  static const int wpars[8] = {1, 1, 1, 1, 0, 0, 0, 0};
  static const int sigbs[8] = {8, 8, 8, 8, 4, 2, 2, 0};

  Params P;
  P.x0 = x;
  P.Wih[0] = Wih0; P.Whh[0] = Whh0; P.bih[0] = bih0; P.bhh[0] = bhh0;
  for (int i = 0; i < 7; ++i) {
    P.Wih[i + 1] = WihA + (size_t)i * HID * HID;
    P.Whh[i + 1] = WhhA + (size_t)i * HID * HID;
    P.bih[i + 1] = bihA + (size_t)i * HID;
    P.bhh[i + 1] = bhhA + (size_t)i * HID;
  }
  for (int i = 0; i < 8; ++i) {
    P.jmax[i] = jmaxs[i]; P.wpar[i] = wpars[i]; P.sigb[i] = sigbs[i];
  }

  // workspace: per-layer slot-compacted hi/lo planes (~102 MB) + hlast + flags
  unsigned short* wsp = (unsigned short*)d_ws;
  size_t off = 0;
  for (int i = 0; i < 7; ++i) {
    const size_t slots = (size_t)jmaxs[i + 1] * NBATCH * HID;
    P.phi[i] = wsp + off; off += slots;
    P.plo[i] = wsp + off; off += slots;
  }
  P.phi[7] = nullptr; P.plo[7] = nullptr;
  P.hlast = (float*)(wsp + off); off += (size_t)NBATCH * HID * 2;  // f32 = 2 shorts
  int* flags = (int*)(wsp + off);
  P.flags = flags;

  // allow >64KB dynamic LDS (84KB: CU-exclusive + L0 x-slab)
  hipFuncSetAttribute((const void*)drnn_fused,
                      hipFuncAttributeMaxDynamicSharedMemorySize, DYN_LDS);

  hipMemsetAsync(flags, 0, 7 * 16 * 64 * sizeof(int), stream);
  drnn_fused<<<dim3(128), dim3(256), DYN_LDS, stream>>>(P);
  logits_kernel<<<dim3(1), dim3(256), 0, stream>>>(P.hlast, Wout, bout, out);
}

// Round 12
// 924.252 us; speedup vs baseline: 3.0442x; 1.0390x over previous
//
#include <hip/hip_runtime.h>

// Dilated RNN forward, MI355X. Round 11 (resubmit — bench never acquired a
// GPU): chain-shortening via f16 + kb-trees.
//  - R8/R10 structure: 128 WGs = 8 pruned layers x 16 batch-groups, pipelined
//    via batched delayed L3-coherent flags; 84KB LDS (CU-exclusive); L0 x-slab
//    in LDS; SYSTEM-scope write-through plane stores.
//  - NEW (latency-chain diet; step was ~85% issue-idle = dependency-bound):
//    (a) f16 arithmetic: W single-term f16 (12-bit, systematic error ~1e-4
//        steady-state under contraction), h/x two-term f16 hi+lo (22-bit,
//        better than old bf16 hi+lo=16). 3 MFMA products -> 2.
//    (b) per-kb accumulators + 2-level f32x4 add tree: post-barrier MFMA
//        dependent depth = 2 (was 4); non-L0 absorbs x-product depth
//        pre-barrier into the same accumulators.

typedef __attribute__((ext_vector_type(8))) _Float16 f16x8;
typedef __attribute__((ext_vector_type(4))) _Float16 f16x4;
typedef __attribute__((ext_vector_type(4))) float f32x4;
typedef __attribute__((ext_vector_type(2))) unsigned long long u64x2;

#define TSTEPS 784
#define NBATCH 256
#define HID 128
#define SLOT_ELEMS (NBATCH * HID)     // shorts per plane slot (32768)
#define XPITCH 788                    // f32 pitch for L0 x slab (2-way banks)
#define DYN_LDS 86016                 // 84KB -> 1 WG/CU; also fits x-slab

struct Params {
  const float* x0;
  const float* Wih[8];
  const float* Whh[8];
  const float* bih[8];
  const float* bhh[8];
  unsigned short* phi[8];  // slot-indexed output plane of layer i (i<7), f16 bits
  unsigned short* plo[8];
  float* hlast;
  int* flags;              // flag (layer i -> i+1, bg) at [(i*16+bg)*64]
  int jmax[8];
  int wpar[8];
  int sigb[8];             // producer signal batch (slots)
};

// LDS-only barrier: drain own ds ops, sync; global traffic stays in flight.
__device__ __forceinline__ void lds_barrier() {
  asm volatile("s_waitcnt lgkmcnt(0)" ::: "memory");
  __builtin_amdgcn_s_barrier();
  asm volatile("" ::: "memory");
}
__device__ __forceinline__ float tanh_fast(float v) {
  float t  = __builtin_amdgcn_exp2f(v * 2.885390081777927f);
  float rc = __builtin_amdgcn_rcpf(t + 1.0f);
  return __builtin_fmaf(-2.0f, rc, 1.0f);
}
__device__ __forceinline__ f16x8 load_wf16(const float* __restrict__ p) {
  f16x8 w;
#pragma unroll
  for (int i = 0; i < 8; ++i) w[i] = (_Float16)p[i];  // RTNE
  return w;
}

// Fused pipeline. Grid: 128 WGs x 256 threads. WG -> (layer, batch-group).
// Lane-convention triple verified R1-R10 (A row=l&15; B col=l&15;
// k = kb*32+(l>>4)*8+s; C: value r of lane l -> row (l>>4)*4+r, col l&15).
// f16 fragment/C-D layout is shape-determined, dtype-independent (m121/m127).
__global__ __launch_bounds__(256, 1) void drnn_fused(Params P) {
  extern __shared__ __align__(16) char smem[];
  unsigned short (*Hhi)[16][136] = (unsigned short(*)[16][136])smem;          // 8704B
  unsigned short (*Hlo)[16][136] = (unsigned short(*)[16][136])(smem + 8704); // 8704B
  float* xlds = (float*)(smem + 17408);  // L0 only: [16][XPITCH] f32 = 50432B

  const int layer  = blockIdx.x >> 4;
  const int bg     = blockIdx.x & 15;
  const bool isL0   = (layer == 0);
  const bool isLast = (layer == 7);
  const int jmax = P.jmax[layer];
  const int wpar = P.wpar[layer];
  const int SIGB = P.sigb[layer];
  const float* __restrict__ Wih = P.Wih[layer];
  const float* __restrict__ Whh = P.Whh[layer];
  const float* __restrict__ bih = P.bih[layer];
  const float* __restrict__ bhh = P.bhh[layer];
  const unsigned short* __restrict__ Yin_hi = isL0 ? nullptr : P.phi[layer - 1];
  const unsigned short* __restrict__ Yin_lo = isL0 ? nullptr : P.plo[layer - 1];
  unsigned short* __restrict__ Yout_hi = isLast ? nullptr : P.phi[layer];
  unsigned short* __restrict__ Yout_lo = isLast ? nullptr : P.plo[layer];
  int* fin  = isL0 ? nullptr : P.flags + 64 * ((layer - 1) * 16 + bg);
  int* fout = isLast ? nullptr : P.flags + 64 * (layer * 16 + bg);

  const int tid  = threadIdx.x;
  const int wave = tid >> 6;      // 0..3
  const int lane = tid & 63;
  const int lrow = lane & 15;     // A row / B col / C col (batch)
  const int lgrp = lane >> 4;     // k-slot group; C row group
  const int b0   = bg << 4;

  // consumer flag cache: SYSTEM relaxed poll (L3 read, no cache maintenance)
  int seen = 0;
  auto wait_in = [&](int need) {
    if (seen >= need) return;
    while ((seen = __hip_atomic_load(fin, __ATOMIC_RELAXED,
                                     __HIP_MEMORY_SCOPE_SYSTEM)) < need)
      __builtin_amdgcn_s_sleep(2);
  };

  // ---- persistent weight A-frags (single-term f16) ----
  f16x8 whh[2][4], wih[2][4];
#pragma unroll
  for (int tl = 0; tl < 2; ++tl) {
    const float* wp = Whh + (size_t)(wave * 32 + tl * 16 + lrow) * HID + lgrp * 8;
#pragma unroll
    for (int kb = 0; kb < 4; ++kb)
      whh[tl][kb] = load_wf16(wp + kb * 32);
  }
  if (!isL0) {
#pragma unroll
    for (int tl = 0; tl < 2; ++tl) {
      const float* wp = Wih + (size_t)(wave * 32 + tl * 16 + lrow) * HID + lgrp * 8;
#pragma unroll
      for (int kb = 0; kb < 4; ++kb)
        wih[tl][kb] = load_wf16(wp + kb * 32);
    }
  }
  f32x4 bias_[2], w0_[2];
#pragma unroll
  for (int tl = 0; tl < 2; ++tl)
#pragma unroll
    for (int r = 0; r < 4; ++r) {
      const int n = wave * 32 + tl * 16 + lgrp * 4 + r;
      bias_[tl][r] = bih[n] + bhh[n];
      w0_[tl][r]   = isL0 ? Wih[n] : 0.0f;
    }

  // L0: preload this WG's x slice into LDS (removes all L0 global loads)
  if (isL0) {
    for (int r = 0; r < 16; ++r)
      for (int i = tid; i < TSTEPS / 4; i += 256)
        *(f32x4*)&xlds[r * XPITCH + i * 4] =
            *(const f32x4*)&P.x0[(size_t)(b0 + r) * TSTEPS + i * 4];
    __syncthreads();
  }

  // x double-buffer (running-pointer plane prefetch; L0 reads LDS slab)
  f16x8 xhA[4], xlA[4], xhB[4], xlB[4];
  float xvA = 0.f, xvB = 0.f;
  const unsigned short* pin_h = nullptr;
  const unsigned short* pin_l = nullptr;
  if (isL0) {
    xvA = xlds[lrow * XPITCH + 0];
  } else {
    wait_in(1);
    const size_t lofs = ((size_t)b0 + lrow) * HID + lgrp * 8;
    pin_h = Yin_hi + lofs;
    pin_l = Yin_lo + lofs;
#pragma unroll
    for (int kb = 0; kb < 4; ++kb) {
      xhA[kb] = *(const f16x8*)(pin_h + kb * 32);
      xlA[kb] = *(const f16x8*)(pin_l + kb * 32);
    }
    pin_h += SLOT_ELEMS;  // -> slot 1
    pin_l += SLOT_ELEMS;
  }

  // running-pointer coalesced writeback; SYSTEM-scope 8B stores (write-
  // through to L3 -> cross-XCD visible without any cache maintenance)
  unsigned long long* wb_h = nullptr;
  unsigned long long* wb_l = nullptr;
  if (!isLast) {
    const int row = tid >> 4, cb = tid & 15;
    const size_t wofs = ((size_t)b0 + row) * HID + cb * 8;
    wb_h = (unsigned long long*)(Yout_hi + wofs);
    wb_l = (unsigned long long*)(Yout_lo + wofs);
  }
  const int wsrc = (tid >> 4) * 136 + (tid & 15) * 8;  // LDS src offset (shorts)
  auto writeback = [&](int rp) {
    u64x2 vh = *(const u64x2*)((const unsigned short*)&Hhi[rp][0][0] + wsrc);
    u64x2 vl = *(const u64x2*)((const unsigned short*)&Hlo[rp][0][0] + wsrc);
    __hip_atomic_store(wb_h,     vh[0], __ATOMIC_RELAXED, __HIP_MEMORY_SCOPE_SYSTEM);
    __hip_atomic_store(wb_h + 1, vh[1], __ATOMIC_RELAXED, __HIP_MEMORY_SCOPE_SYSTEM);
    __hip_atomic_store(wb_l,     vl[0], __ATOMIC_RELAXED, __HIP_MEMORY_SCOPE_SYSTEM);
    __hip_atomic_store(wb_l + 1, vl[1], __ATOMIC_RELAXED, __HIP_MEMORY_SCOPE_SYSTEM);
    wb_h += SLOT_ELEMS / 4;   // shorts -> u64 units
    wb_l += SLOT_ELEMS / 4;
  };
  // signal: per-wave drain of (old, long-acked) stores; barrier; bare flag
  auto signal = [&](int val) {
    asm volatile("s_waitcnt vmcnt(0)" ::: "memory");
    __builtin_amdgcn_s_barrier();
    if (tid == 0)
      __hip_atomic_store(fout, val, __ATOMIC_RELAXED, __HIP_MEMORY_SCOPE_SYSTEM);
  };

  int next_sig = SIGB;  // first in-loop signal when about to write slot SIGB

  auto step = [&](int j, f16x8 (&xh_c)[4], f16x8 (&xl_c)[4],
                  f16x8 (&xh_n)[4], f16x8 (&xl_n)[4],
                  float& xv_c, float& xv_n) {
    // prefetch input for step j+1 (gated by producer flag for slot j+1)
    if (j + 1 < jmax) {
      if (isL0) {
        xv_n = xlds[lrow * XPITCH + (j + 1)];
      } else {
        wait_in(j + 2);
#pragma unroll
        for (int kb = 0; kb < 4; ++kb) {
          xh_n[kb] = *(const f16x8*)(pin_h + kb * 32);
          xl_n[kb] = *(const f16x8*)(pin_l + kb * 32);
        }
        pin_h += SLOT_ELEMS;
        pin_l += SLOT_ELEMS;
      }
    }
    // per-kb accumulators: bias folded into kb=0; post-barrier depth = 2
    f32x4 c[2][4];
#pragma unroll
    for (int tl = 0; tl < 2; ++tl) {
      c[tl][0] = bias_[tl];
#pragma unroll
      for (int kb = 1; kb < 4; ++kb) c[tl][kb] = f32x4{0.f, 0.f, 0.f, 0.f};
    }
    if (!isL0) {  // xW before the barrier (absorbed depth: +2 per kb-acc)
#pragma unroll
      for (int kb = 0; kb < 4; ++kb)
#pragma unroll
        for (int tl = 0; tl < 2; ++tl) {
          c[tl][kb] = __builtin_amdgcn_mfma_f32_16x16x32_f16(wih[tl][kb], xh_c[kb], c[tl][kb], 0, 0, 0);
          c[tl][kb] = __builtin_amdgcn_mfma_f32_16x16x32_f16(wih[tl][kb], xl_c[kb], c[tl][kb], 0, 0, 0);
        }
    }
    if (j > 0) {
      lds_barrier();  // H[rp] visible; global traffic stays in flight
      const int rp = (j - 1) & 1;
      f16x8 bh[4], bl[4];
#pragma unroll
      for (int kb = 0; kb < 4; ++kb)   // bh first: chains start on partial lgkm
        bh[kb] = *(const f16x8*)&Hhi[rp][lrow][kb * 32 + lgrp * 8];
#pragma unroll
      for (int kb = 0; kb < 4; ++kb)
        bl[kb] = *(const f16x8*)&Hlo[rp][lrow][kb * 32 + lgrp * 8];
      // 8 independent 2-deep chains (tl x kb): latency path = 2*L_mfma
#pragma unroll
      for (int kb = 0; kb < 4; ++kb)
#pragma unroll
        for (int tl = 0; tl < 2; ++tl) {
          c[tl][kb] = __builtin_amdgcn_mfma_f32_16x16x32_f16(whh[tl][kb], bh[kb], c[tl][kb], 0, 0, 0);
          c[tl][kb] = __builtin_amdgcn_mfma_f32_16x16x32_f16(whh[tl][kb], bl[kb], c[tl][kb], 0, 0, 0);
        }
      if (!isLast && ((j - 1) & 1) == wpar) {
        const int wbslot = (j - 1 - wpar) >> 1;
        if (wbslot == next_sig) {
          signal(wbslot);   // covers slots [0, wbslot), stores long acked
          next_sig += SIGB;
        }
        writeback(rp);
      }
    }
    // tree-combine + tanh + f16 hi/lo split + LDS store
    const int pp = j & 1;
#pragma unroll
    for (int tl = 0; tl < 2; ++tl) {
      f32x4 v = (c[tl][0] + c[tl][1]) + (c[tl][2] + c[tl][3]);
      f16x4 h4, l4;
      f32x4 yv;
#pragma unroll
      for (int r = 0; r < 4; ++r) {
        float vv = v[r];
        if (isL0) vv = __builtin_fmaf(xv_c, w0_[tl][r], vv);
        const float y = tanh_fast(vv);
        yv[r] = y;
        const _Float16 hh = (_Float16)y;          // RTNE, rel err <= 2^-12
        const float rem = y - (float)hh;          // exact
        h4[r] = hh;
        l4[r] = (_Float16)rem;                    // residual <= 2^-23 rel
      }
      const int nb = wave * 32 + tl * 16 + lgrp * 4;   // 8B-aligned (4 shorts)
      *(f16x4*)&Hhi[pp][lrow][nb] = h4;
      *(f16x4*)&Hlo[pp][lrow][nb] = l4;
      if (isLast && j == jmax - 1)
        *(f32x4*)&P.hlast[(size_t)(b0 + lrow) * HID + nb] = yv;
    }
  };

  int j = 0;
  for (;;) {
    step(j, xhA, xlA, xhB, xlB, xvA, xvB);
    if (++j >= jmax) break;
    step(j, xhB, xlB, xhA, xlA, xvB, xvA);
    if (++j >= jmax) break;
  }

  if (!isLast) {
    if (((jmax - 1) & 1) == wpar) {  // last step's state, if consumed
      lds_barrier();
      writeback((jmax - 1) & 1);
    }
    signal(((jmax - 1 - wpar) >> 1) + 1);  // all slots ready
  }
}

// logits[b][n] = sum_k hlast[b][k] * W[k][n] + b[n]
__global__ __launch_bounds__(256) void logits_kernel(
    const float* __restrict__ hlast, const float* __restrict__ W,
    const float* __restrict__ bvec, float* __restrict__ out)
{
  __shared__ float Ws[HID * 10];
  const int tid = threadIdx.x;
  for (int i = tid; i < HID * 10; i += 256) Ws[i] = W[i];
  __syncthreads();
  float acc[10];
#pragma unroll
  for (int n = 0; n < 10; ++n) acc[n] = bvec[n];
  const float* h = hlast + (size_t)tid * HID;
#pragma unroll 4
  for (int k = 0; k < HID; ++k) {
    const float hv = h[k];
#pragma unroll
    for (int n = 0; n < 10; ++n) acc[n] += hv * Ws[k * 10 + n];
  }
#pragma unroll
  for (int n = 0; n < 10; ++n) out[(size_t)tid * 10 + n] = acc[n];
}

extern "C" void kernel_launch(void* const* d_in, const int* in_sizes, int n_in,
                              void* d_out, int out_size, void* d_ws, size_t ws_size,
                              hipStream_t stream) {
  (void)in_sizes; (void)n_in; (void)out_size; (void)ws_size;
  const float* x    = (const float*)d_in[0];   // (256,784,1)
  const float* Wih0 = (const float*)d_in[1];   // (128,1)
  const float* Whh0 = (const float*)d_in[2];   // (128,128)
  const float* bih0 = (const float*)d_in[3];
  const float* bhh0 = (const float*)d_in[4];
  const float* WihA = (const float*)d_in[5];   // (7,128,128)
  const float* WhhA = (const float*)d_in[6];   // (7,128,128)
  const float* bihA = (const float*)d_in[7];   // (7,128)
  const float* bhhA = (const float*)d_in[8];   // (7,128)
  const float* Wout = (const float*)d_in[9];   // (128,10)
  const float* bout = (const float*)d_in[10];  // (10,)
  float* out = (float*)d_out;

  // Pruned chains (R4 dataflow): chain c = 0,1,3,7,15,15,15,15
  static const int jmaxs[8] = {784, 392, 196, 98, 49, 25, 13, 7};
  static const int wpars[8] = {1, 1, 1, 1, 0, 0, 0, 0};
  static const int sigbs[8] = {8, 8, 8, 8, 4, 2, 2, 0};

  Params P;
  P.x0 = x;
  P.Wih[0] = Wih0; P.Whh[0] = Whh0; P.bih[0] = bih0; P.bhh[0] = bhh0;
  for (int i = 0; i < 7; ++i) {
    P.Wih[i + 1] = WihA + (size_t)i * HID * HID;
    P.Whh[i + 1] = WhhA + (size_t)i * HID * HID;
    P.bih[i + 1] = bihA + (size_t)i * HID;
    P.bhh[i + 1] = bhhA + (size_t)i * HID;
  }
  for (int i = 0; i < 8; ++i) {
    P.jmax[i] = jmaxs[i]; P.wpar[i] = wpars[i]; P.sigb[i] = sigbs[i];
  }

  // workspace: per-layer slot-compacted hi/lo planes (~102 MB) + hlast + flags
  unsigned short* wsp = (unsigned short*)d_ws;
  size_t off = 0;
  for (int i = 0; i < 7; ++i) {
    const size_t slots = (size_t)jmaxs[i + 1] * NBATCH * HID;
    P.phi[i] = wsp + off; off += slots;
    P.plo[i] = wsp + off; off += slots;
  }
  P.phi[7] = nullptr; P.plo[7] = nullptr;
  P.hlast = (float*)(wsp + off); off += (size_t)NBATCH * HID * 2;  // f32 = 2 shorts
  int* flags = (int*)(wsp + off);
  P.flags = flags;

  // allow >64KB dynamic LDS (84KB: CU-exclusive + L0 x-slab)
  hipFuncSetAttribute((const void*)drnn_fused,
                      hipFuncAttributeMaxDynamicSharedMemorySize, DYN_LDS);

  hipMemsetAsync(flags, 0, 7 * 16 * 64 * sizeof(int), stream);
  drnn_fused<<<dim3(128), dim3(256), DYN_LDS, stream>>>(P);
  logits_kernel<<<dim3(1), dim3(256), 0, stream>>>(P.hlast, Wout, bout, out);
}